// Round 8
// baseline (233.596 us; speedup 1.0000x reference)
//
#include <hip/hip_runtime.h>
#include <math.h>

#define B_  8
#define H_  8
#define C_  512
#define L_  1024
#define DH  64
#define WIN 4

typedef __attribute__((ext_vector_type(8))) short short8;
typedef __attribute__((ext_vector_type(4))) float floatx4;

__device__ __forceinline__ unsigned short f2bf(float f) {
    unsigned int u = __float_as_uint(f);
    u = u + 0x7FFFu + ((u >> 16) & 1u);     // RNE
    return (unsigned short)(u >> 16);
}
__device__ __forceinline__ float bf2f(unsigned short h) {
    return __uint_as_float(((unsigned int)h) << 16);
}

// ---------------------------------------------------------------------------
// prep: Wq/Wk/Wv -> bf16 hi (packed 3x512x512), Wo -> hi+lo, pack biases.
// ---------------------------------------------------------------------------
__global__ __launch_bounds__(256) void prep_kernel(
    const float* __restrict__ Wq, const float* __restrict__ Wk,
    const float* __restrict__ Wv, const float* __restrict__ Wo,
    const float* __restrict__ bq, const float* __restrict__ bk,
    const float* __restrict__ bv,
    unsigned short* __restrict__ Wqkv_hi,
    unsigned short* __restrict__ Wo_hi, unsigned short* __restrict__ Wo_lo,
    float* __restrict__ bqkv)
{
    const int i = blockIdx.x * 256 + threadIdx.x;   // 65536 float4 slots
    float4 v; ushort4 h;

    v = ((const float4*)Wq)[i];
    h.x = f2bf(v.x); h.y = f2bf(v.y); h.z = f2bf(v.z); h.w = f2bf(v.w);
    ((ushort4*)Wqkv_hi)[i] = h;

    v = ((const float4*)Wk)[i];
    h.x = f2bf(v.x); h.y = f2bf(v.y); h.z = f2bf(v.z); h.w = f2bf(v.w);
    ((ushort4*)Wqkv_hi)[65536 + i] = h;

    v = ((const float4*)Wv)[i];
    h.x = f2bf(v.x); h.y = f2bf(v.y); h.z = f2bf(v.z); h.w = f2bf(v.w);
    ((ushort4*)Wqkv_hi)[131072 + i] = h;

    v = ((const float4*)Wo)[i];
    h.x = f2bf(v.x); h.y = f2bf(v.y); h.z = f2bf(v.z); h.w = f2bf(v.w);
    ((ushort4*)Wo_hi)[i] = h;
    ushort4 lo;
    lo.x = f2bf(v.x - bf2f(h.x)); lo.y = f2bf(v.y - bf2f(h.y));
    lo.z = f2bf(v.z - bf2f(h.z)); lo.w = f2bf(v.w - bf2f(h.w));
    ((ushort4*)Wo_lo)[i] = lo;

    if (i < 512)       bqkv[i] = bq[i];
    else if (i < 1024) bqkv[i] = bk[i - 512];
    else if (i < 1536) bqkv[i] = bv[i - 1024];
}

// ---------------------------------------------------------------------------
// x (B,C,L) fp32 -> xT bf16 (B,L,C).  32x32 LDS transpose.
// ---------------------------------------------------------------------------
__global__ __launch_bounds__(256) void transpose_kernel(
    const float* __restrict__ x, unsigned short* __restrict__ xT)
{
    __shared__ float tile[32][33];
    const int b  = blockIdx.z;
    const int cb = blockIdx.y * 32;
    const int lb = blockIdx.x * 32;
    const int t  = threadIdx.x;
    {
        const int l = t & 31, c0 = t >> 5;
#pragma unroll
        for (int p = 0; p < 4; ++p) {
            const int c = c0 + 8 * p;
            tile[c][l] = x[((size_t)b * C_ + cb + c) * L_ + lb + l];
        }
    }
    __syncthreads();
    {
        const int c = t & 31, l0 = t >> 5;
#pragma unroll
        for (int p = 0; p < 4; ++p) {
            const int l = l0 + 8 * p;
            xT[((size_t)b * L_ + lb + l) * C_ + cb + c] = f2bf(tile[c][l]);
        }
    }
}

// ---------------------------------------------------------------------------
// Fused QKV GEMM, plain bf16.  M=1536 x N=1024 x K=512.
// Q,K: LDS-transposed epilogue -> coalesced (B,H,L,Dh) bf16 (Q pre-scaled).
// V:   direct coalesced (B,C,L) bf16.
// ---------------------------------------------------------------------------
__global__ __launch_bounds__(256) void qkv_gemm_kernel(
    const unsigned short* __restrict__ Wh, const float* __restrict__ bqkv,
    const unsigned short* __restrict__ xT,
    unsigned short* __restrict__ Qb, unsigned short* __restrict__ Kb,
    unsigned short* __restrict__ Vc)
{
    __shared__ __align__(16) unsigned short As[128][40];
    __shared__ __align__(16) unsigned short Bs[128][40];
    __shared__ __align__(16) unsigned short sT[128][66];   // transpose buffer

    const int b   = blockIdx.z;
    const int oB  = blockIdx.y * 128;
    const int mat = oB >> 9;                // 0=Q,1=K,2=V
    const int ob  = oB & 511;
    const int lb  = blockIdx.x * 128;
    const int t  = threadIdx.x;
    const int w = t >> 6, lane = t & 63, quad = lane >> 4, lc = lane & 15;
    const int wm = w >> 1, wn = w & 1;

    const unsigned short* Wm = Wh + (size_t)mat * C_ * C_;

    floatx4 acc[4][4];
#pragma unroll
    for (int i = 0; i < 4; ++i)
#pragma unroll
        for (int j = 0; j < 4; ++j) acc[i][j] = (floatx4)0.f;

    const int c8 = (t & 3) * 8, r0 = t >> 2;
    for (int c0 = 0; c0 < C_; c0 += 32) {
#pragma unroll
        for (int p = 0; p < 2; ++p) {
            *reinterpret_cast<uint4*>(&As[r0 + 64 * p][c8]) =
                *reinterpret_cast<const uint4*>(&Wm[(size_t)(ob + r0 + 64 * p) * C_ + c0 + c8]);
            *reinterpret_cast<uint4*>(&Bs[r0 + 64 * p][c8]) =
                *reinterpret_cast<const uint4*>(&xT[((size_t)b * L_ + lb + r0 + 64 * p) * C_ + c0 + c8]);
        }
        __syncthreads();

        short8 a[4], bb[4];
#pragma unroll
        for (int mt = 0; mt < 4; ++mt)
            a[mt] = *reinterpret_cast<const short8*>(&As[wm * 64 + mt * 16 + lc][quad * 8]);
#pragma unroll
        for (int nt = 0; nt < 4; ++nt)
            bb[nt] = *reinterpret_cast<const short8*>(&Bs[wn * 64 + nt * 16 + lc][quad * 8]);
#pragma unroll
        for (int mt = 0; mt < 4; ++mt)
#pragma unroll
            for (int nt = 0; nt < 4; ++nt)
                acc[mt][nt] = __builtin_amdgcn_mfma_f32_16x16x32_bf16(a[mt], bb[nt], acc[mt][nt], 0, 0, 0);
        __syncthreads();
    }

    if (mat == 2) {
        // V: direct coalesced (B,C,L)
#pragma unroll
        for (int mt = 0; mt < 4; ++mt) {
#pragma unroll
            for (int r = 0; r < 4; ++r) {
                const int o  = ob + wm * 64 + mt * 16 + quad * 4 + r;
                const float bi = bqkv[1024 + o];
#pragma unroll
                for (int nt = 0; nt < 4; ++nt) {
                    const int l = lb + wn * 64 + nt * 16 + lc;
                    Vc[((size_t)b * C_ + o) * L_ + l] = f2bf(acc[mt][nt][r] + bi);
                }
            }
        }
    } else {
        // Q/K: per-head LDS transpose, then coalesced (B,H,L,Dh) stores
        const float scale = (mat == 0) ? 0.125f : 1.0f;
        unsigned short* dst = (mat == 0) ? Qb : Kb;
#pragma unroll
        for (int hh = 0; hh < 2; ++hh) {
            if (wm == hh) {
#pragma unroll
                for (int mt = 0; mt < 4; ++mt) {
#pragma unroll
                    for (int r = 0; r < 4; ++r) {
                        const int o  = ob + hh * 64 + mt * 16 + quad * 4 + r;
                        const float bi = bqkv[mat * 512 + o];
                        const int d  = mt * 16 + quad * 4 + r;
#pragma unroll
                        for (int nt = 0; nt < 4; ++nt) {
                            const int l = wn * 64 + nt * 16 + lc;
                            sT[l][d] = f2bf((acc[mt][nt][r] + bi) * scale);
                        }
                    }
                }
            }
            __syncthreads();
            {
                const int l  = t >> 1, hf = t & 1;
                const int h  = (ob >> 6) + hh;
                const size_t o = (((size_t)b * H_ + h) * L_ + lb + l) * DH + hf * 32;
                uint4 v0 = *reinterpret_cast<const uint4*>(&sT[l][hf * 32]);
                uint4 v1 = *reinterpret_cast<const uint4*>(&sT[l][hf * 32 + 8]);
                uint4 v2 = *reinterpret_cast<const uint4*>(&sT[l][hf * 32 + 16]);
                uint4 v3 = *reinterpret_cast<const uint4*>(&sT[l][hf * 32 + 24]);
                *reinterpret_cast<uint4*>(&dst[o])      = v0;
                *reinterpret_cast<uint4*>(&dst[o + 8])  = v1;
                *reinterpret_cast<uint4*>(&dst[o + 16]) = v2;
                *reinterpret_cast<uint4*>(&dst[o + 24]) = v3;
            }
            __syncthreads();
        }
    }
}

// ---------------------------------------------------------------------------
// Attention v6: R6 structure, occupancy-tuned.
// grid (bh 64, rt 16) = 1024 blocks (id%8==h -> XCD L2 locality).
// 256 thr / 4 waves; 64 q-rows per block, 16 per wave (1 row-group).
// K/V double-buffered LDS tiles (64 keys), one barrier/tile, ~50KB LDS
// -> 3 blocks/CU = 12 waves (vs R6's 5.6 avg): latency-chain coverage.
// No-max softmax; row-sums via ones-MFMA; rel-k/rel-v gated near-diagonal.
// ---------------------------------------------------------------------------
__global__ __launch_bounds__(256) void attn_kernel6(
    const unsigned short* __restrict__ Qb,   // bf16 (B,H,L,Dh), pre-scaled
    const unsigned short* __restrict__ Kb,   // bf16 (B,H,L,Dh)
    const unsigned short* __restrict__ Vc,   // bf16 (B,C,L)
    const float* __restrict__ erel_k, const float* __restrict__ erel_v,
    unsigned short* __restrict__ AOh, unsigned short* __restrict__ AOl)
{
    __shared__ __align__(16) unsigned short kst[2][64][72];  // [buf][j][d]
    __shared__ __align__(16) unsigned short vst[2][64][72];  // [buf][d][j]
    __shared__ __align__(16) unsigned short Pl[4][16][72];   // per-wave P
    __shared__ float rs[64][9];
    __shared__ float rv[64][9];

    const int t  = threadIdx.x;
    const int bh = blockIdx.x;          // 0..63
    const int rt = blockIdx.y;          // 0..15
    const int b = bh >> 3, h = bh & 7;
    const int w = t >> 6, lane = t & 63, quad = lane >> 4, lc = lane & 15;
    const int row0 = rt * 64;
    const int rowW = row0 + w * 16;

    const size_t qkBase = (size_t)bh * L_ * DH;
    const size_t vBase  = ((size_t)b * C_ + h * DH) * L_;

    for (int i = lane; i < 16 * 9; i += 64) rv[w * 16 + i / 9][i % 9] = 0.f;

    // Q A-fragments (rows rowW+lc), reused across all 16 tiles
    short8 af[2];
#pragma unroll
    for (int kk = 0; kk < 2; ++kk)
        af[kk] = *reinterpret_cast<const short8*>(
            &Qb[qkBase + (size_t)(rowW + lc) * DH + kk * 32 + quad * 8]);

    // rel-k scores via MFMA: B[n=dr][k=d] = erk[dr][d]
    {
        floatx4 rsa = (floatx4)0.f;
        const int drow = (lc < 9) ? lc : 8;
#pragma unroll
        for (int kk = 0; kk < 2; ++kk) {
            short8 bfr;
#pragma unroll
            for (int i = 0; i < 8; ++i)
                bfr[i] = (short)f2bf(erel_k[drow * 64 + kk * 32 + quad * 8 + i]);
            rsa = __builtin_amdgcn_mfma_f32_16x16x32_bf16(af[kk], bfr, rsa, 0, 0, 0);
        }
        if (lc < 9) {
#pragma unroll
            for (int r = 0; r < 4; ++r)
                rs[w * 16 + quad * 4 + r][lc] = rsa[r];
        }
    }

    // stage tile 0 into buffer 0
    const int jr = t >> 3, jc = (t & 7) * 8;
#pragma unroll
    for (int p = 0; p < 2; ++p) {
        *reinterpret_cast<uint4*>(&kst[0][jr + 32 * p][jc]) =
            *reinterpret_cast<const uint4*>(&Kb[qkBase + (size_t)(jr + 32 * p) * DH + jc]);
        *reinterpret_cast<uint4*>(&vst[0][jr + 32 * p][jc]) =
            *reinterpret_cast<const uint4*>(&Vc[vBase + (size_t)(jr + 32 * p) * L_ + jc]);
    }
    __syncthreads();

    short8 ones;
#pragma unroll
    for (int j = 0; j < 8; ++j) ones[j] = (short)0x3F80;

    floatx4 acc_o[4], acc_l = (floatx4)0.f;
#pragma unroll
    for (int nt = 0; nt < 4; ++nt) acc_o[nt] = (floatx4)0.f;

    for (int jt = 0; jt < L_ / 64; ++jt) {
        const int j0  = jt * 64;
        const int cur = jt & 1;

        // register prefetch of next tile
        uint4 pk[2], pv[2];
        if (jt < L_ / 64 - 1) {
            const int j0n = j0 + 64;
#pragma unroll
            for (int p = 0; p < 2; ++p) {
                pk[p] = *reinterpret_cast<const uint4*>(
                    &Kb[qkBase + (size_t)(j0n + jr + 32 * p) * DH + jc]);
                pv[p] = *reinterpret_cast<const uint4*>(
                    &Vc[vBase + (size_t)(jr + 32 * p) * L_ + j0n + jc]);
            }
        }

        // S = Q K^T
        floatx4 sacc[4];
#pragma unroll
        for (int nt = 0; nt < 4; ++nt) sacc[nt] = (floatx4)0.f;
#pragma unroll
        for (int nt = 0; nt < 4; ++nt)
#pragma unroll
            for (int kk = 0; kk < 2; ++kk) {
                const short8 kf = *reinterpret_cast<const short8*>(
                    &kst[cur][nt * 16 + lc][kk * 32 + quad * 8]);
                sacc[nt] = __builtin_amdgcn_mfma_f32_16x16x32_bf16(af[kk], kf, sacc[nt], 0, 0, 0);
            }

        // windowed rel-k bias (near-diagonal tiles only)
        const bool nearD = (j0 <= rowW + 15 + WIN) && (j0 + 63 >= rowW - WIN);
        if (nearD) {
#pragma unroll
            for (int nt = 0; nt < 4; ++nt) {
                const int jg = j0 + nt * 16 + lc;
#pragma unroll
                for (int r = 0; r < 4; ++r) {
                    const int diff = jg - (rowW + quad * 4 + r);
                    if (diff >= -WIN && diff <= WIN)
                        sacc[nt][r] += rs[w * 16 + quad * 4 + r][diff + WIN];
                }
            }
        }

        // exp (no max subtraction), P -> LDS bf16
#pragma unroll
        for (int nt = 0; nt < 4; ++nt)
#pragma unroll
            for (int r = 0; r < 4; ++r)
                Pl[w][quad * 4 + r][nt * 16 + lc] = f2bf(__expf(sacc[nt][r]));

        // rel-v prob accumulation (gated; wave-private rows)
        if (nearD) {
            for (int idx = lane; idx < 16 * 9; idx += 64) {
                const int r16 = idx / 9, dr = idx % 9;
                const int jg = row0 + w * 16 + r16 + dr - WIN;
                if (jg >= j0 && jg < j0 + 64 && jg >= 0 && jg < L_)
                    rv[w * 16 + r16][dr] += bf2f(Pl[w][r16][jg - j0]);
            }
        }

        // P back as A-fragments
        short8 pf[2];
#pragma unroll
        for (int kk = 0; kk < 2; ++kk)
            pf[kk] = *reinterpret_cast<const short8*>(&Pl[w][lc][kk * 32 + quad * 8]);

        // row sums via MFMA
#pragma unroll
        for (int kk = 0; kk < 2; ++kk)
            acc_l = __builtin_amdgcn_mfma_f32_16x16x32_bf16(pf[kk], ones, acc_l, 0, 0, 0);

        // O += P V  (V B-frags from LDS)
#pragma unroll
        for (int nt = 0; nt < 4; ++nt)
#pragma unroll
            for (int kk = 0; kk < 2; ++kk) {
                const short8 vf = *reinterpret_cast<const short8*>(
                    &vst[cur][nt * 16 + lc][kk * 32 + quad * 8]);
                acc_o[nt] = __builtin_amdgcn_mfma_f32_16x16x32_bf16(pf[kk], vf, acc_o[nt], 0, 0, 0);
            }

        // commit prefetched tile to the other buffer, then sync
        if (jt < L_ / 64 - 1) {
#pragma unroll
            for (int p = 0; p < 2; ++p) {
                *reinterpret_cast<uint4*>(&kst[1 - cur][jr + 32 * p][jc]) = pk[p];
                *reinterpret_cast<uint4*>(&vst[1 - cur][jr + 32 * p][jc]) = pv[p];
            }
        }
        __syncthreads();
    }

    // epilogue: rel-v term, normalize, write AO hi/lo bf16 (B,L,C)
#pragma unroll
    for (int nt = 0; nt < 4; ++nt) {
        const int d = nt * 16 + lc;
        float ev[9];
#pragma unroll
        for (int dr = 0; dr < 9; ++dr) ev[dr] = erel_v[dr * 64 + d];
#pragma unroll
        for (int r = 0; r < 4; ++r) {
            const int rloc = w * 16 + quad * 4 + r;
            float v = acc_o[nt][r];
#pragma unroll
            for (int dr = 0; dr < 9; ++dr) v += rv[rloc][dr] * ev[dr];
            const float outv = v / acc_l[r];
            const unsigned short hi = f2bf(outv);
            const unsigned short lo = f2bf(outv - bf2f(hi));
            const size_t idx = ((size_t)b * L_ + row0 + rloc) * C_ + h * 64 + d;
            AOh[idx] = hi;
            AOl[idx] = lo;
        }
    }
}

// ---------------------------------------------------------------------------
// Output projection, 3-term hi/lo split.  M=512 x N-tile 64 x K=512.
// ---------------------------------------------------------------------------
__global__ __launch_bounds__(256) void out_gemm_kernel(
    const unsigned short* __restrict__ Wh, const unsigned short* __restrict__ Wl,
    const float* __restrict__ bo,
    const unsigned short* __restrict__ Ah, const unsigned short* __restrict__ Al,
    float* __restrict__ Y)
{
    __shared__ __align__(16) unsigned short As_h[128][40];
    __shared__ __align__(16) unsigned short As_l[128][40];
    __shared__ __align__(16) unsigned short Bs_h[64][40];
    __shared__ __align__(16) unsigned short Bs_l[64][40];

    const int b  = blockIdx.z;
    const int ob = blockIdx.y * 128;
    const int lb = blockIdx.x * 64;
    const int t  = threadIdx.x;
    const int w = t >> 6, lane = t & 63, quad = lane >> 4, lc = lane & 15;
    const int wm = w >> 1, wn = w & 1;

    floatx4 acc[4][2];
#pragma unroll
    for (int i = 0; i < 4; ++i)
#pragma unroll
        for (int j = 0; j < 2; ++j) acc[i][j] = (floatx4)0.f;

    const int c8 = (t & 3) * 8, r0 = t >> 2;
    for (int c0 = 0; c0 < C_; c0 += 32) {
#pragma unroll
        for (int p = 0; p < 2; ++p) {
            *reinterpret_cast<uint4*>(&As_h[r0 + 64 * p][c8]) =
                *reinterpret_cast<const uint4*>(&Wh[(size_t)(ob + r0 + 64 * p) * C_ + c0 + c8]);
            *reinterpret_cast<uint4*>(&As_l[r0 + 64 * p][c8]) =
                *reinterpret_cast<const uint4*>(&Wl[(size_t)(ob + r0 + 64 * p) * C_ + c0 + c8]);
        }
        {
            const size_t g = ((size_t)b * L_ + lb + r0) * C_ + c0 + c8;
            *reinterpret_cast<uint4*>(&Bs_h[r0][c8]) =
                *reinterpret_cast<const uint4*>(&Ah[g]);
            *reinterpret_cast<uint4*>(&Bs_l[r0][c8]) =
                *reinterpret_cast<const uint4*>(&Al[g]);
        }
        __syncthreads();

        short8 ah[4], al[4], bhf[2], blf[2];
#pragma unroll
        for (int mt = 0; mt < 4; ++mt) {
            const int row = wm * 64 + mt * 16 + lc;
            ah[mt] = *reinterpret_cast<const short8*>(&As_h[row][quad * 8]);
            al[mt] = *reinterpret_cast<const short8*>(&As_l[row][quad * 8]);
        }
#pragma unroll
        for (int nt = 0; nt < 2; ++nt) {
            const int row = wn * 32 + nt * 16 + lc;
            bhf[nt] = *reinterpret_cast<const short8*>(&Bs_h[row][quad * 8]);
            blf[nt] = *reinterpret_cast<const short8*>(&Bs_l[row][quad * 8]);
        }
#pragma unroll
        for (int mt = 0; mt < 4; ++mt)
#pragma unroll
            for (int nt = 0; nt < 2; ++nt) {
                acc[mt][nt] = __builtin_amdgcn_mfma_f32_16x16x32_bf16(ah[mt], bhf[nt], acc[mt][nt], 0, 0, 0);
                acc[mt][nt] = __builtin_amdgcn_mfma_f32_16x16x32_bf16(ah[mt], blf[nt], acc[mt][nt], 0, 0, 0);
                acc[mt][nt] = __builtin_amdgcn_mfma_f32_16x16x32_bf16(al[mt], bhf[nt], acc[mt][nt], 0, 0, 0);
            }
        __syncthreads();
    }

#pragma unroll
    for (int mt = 0; mt < 4; ++mt) {
#pragma unroll
        for (int r = 0; r < 4; ++r) {
            const int o = ob + wm * 64 + mt * 16 + quad * 4 + r;
            const float bi = bo[o];
#pragma unroll
            for (int nt = 0; nt < 2; ++nt) {
                const int l = lb + wn * 32 + nt * 16 + lc;
                Y[((size_t)b * C_ + o) * L_ + l] = acc[mt][nt][r] + bi;
            }
        }
    }
}

// ---------------------------------------------------------------------------
extern "C" void kernel_launch(void* const* d_in, const int* in_sizes, int n_in,
                              void* d_out, int out_size, void* d_ws, size_t ws_size,
                              hipStream_t stream)
{
    const float* x   = (const float*)d_in[0];
    const float* Wq  = (const float*)d_in[1];
    const float* bq  = (const float*)d_in[2];
    const float* Wk  = (const float*)d_in[3];
    const float* bk  = (const float*)d_in[4];
    const float* Wv  = (const float*)d_in[5];
    const float* bv  = (const float*)d_in[6];
    const float* Wo  = (const float*)d_in[7];
    const float* bo  = (const float*)d_in[8];
    const float* erk = (const float*)d_in[9];
    const float* erv = (const float*)d_in[10];

    char* ws = (char*)d_ws;
    const size_t MB = 1024u * 1024u;
    unsigned short* xT      = (unsigned short*)(ws);             // 8 MB
    unsigned short* Qb      = (unsigned short*)(ws + 8 * MB);    // 8 MB (B,H,L,Dh)
    unsigned short* Kb      = (unsigned short*)(ws + 16 * MB);   // 8 MB (B,H,L,Dh)
    unsigned short* Vc      = (unsigned short*)(ws + 24 * MB);   // 8 MB (B,C,L)
    unsigned short* AOh     = (unsigned short*)(ws + 32 * MB);   // 8 MB
    unsigned short* AOl     = (unsigned short*)(ws + 40 * MB);   // 8 MB
    unsigned short* Wqkv_hi = (unsigned short*)(ws + 48 * MB);   // 1.5 MB
    unsigned short* Wo_hi   = (unsigned short*)(ws + 50 * MB);   // 0.5 MB
    unsigned short* Wo_lo   = (unsigned short*)(ws + 51 * MB);   // 0.5 MB
    float*          bqkv    = (float*)(ws + 52 * MB);            // 6 KB

    prep_kernel<<<256, 256, 0, stream>>>(Wq, Wk, Wv, Wo, bq, bk, bv,
                                         Wqkv_hi, Wo_hi, Wo_lo, bqkv);
    transpose_kernel<<<dim3(L_ / 32, C_ / 32, B_), 256, 0, stream>>>(x, xT);
    qkv_gemm_kernel<<<dim3(L_ / 128, 12, B_), 256, 0, stream>>>(
        Wqkv_hi, bqkv, xT, Qb, Kb, Vc);
    attn_kernel6<<<dim3(64, 16), 256, 0, stream>>>(
        Qb, Kb, Vc, erk, erv, AOh, AOl);
    out_gemm_kernel<<<dim3(L_ / 64, C_ / 128, B_), 256, 0, stream>>>(
        Wo_hi, Wo_lo, bo, AOh, AOl, (float*)d_out);
}

// Round 9
// 205.940 us; speedup vs baseline: 1.1343x; 1.1343x over previous
//
#include <hip/hip_runtime.h>
#include <math.h>

#define B_  8
#define H_  8
#define C_  512
#define L_  1024
#define DH  64
#define WIN 4

typedef __attribute__((ext_vector_type(8))) short short8;
typedef __attribute__((ext_vector_type(4))) float floatx4;

__device__ __forceinline__ unsigned short f2bf(float f) {
    unsigned int u = __float_as_uint(f);
    u = u + 0x7FFFu + ((u >> 16) & 1u);     // RNE
    return (unsigned short)(u >> 16);
}
__device__ __forceinline__ float bf2f(unsigned short h) {
    return __uint_as_float(((unsigned int)h) << 16);
}

// ---------------------------------------------------------------------------
// prep: Wq/Wk/Wv -> bf16 hi (packed 3x512x512), Wo -> hi+lo, pack biases.
// ---------------------------------------------------------------------------
__global__ __launch_bounds__(256) void prep_kernel(
    const float* __restrict__ Wq, const float* __restrict__ Wk,
    const float* __restrict__ Wv, const float* __restrict__ Wo,
    const float* __restrict__ bq, const float* __restrict__ bk,
    const float* __restrict__ bv,
    unsigned short* __restrict__ Wqkv_hi,
    unsigned short* __restrict__ Wo_hi, unsigned short* __restrict__ Wo_lo,
    float* __restrict__ bqkv)
{
    const int i = blockIdx.x * 256 + threadIdx.x;   // 65536 float4 slots
    float4 v; ushort4 h;

    v = ((const float4*)Wq)[i];
    h.x = f2bf(v.x); h.y = f2bf(v.y); h.z = f2bf(v.z); h.w = f2bf(v.w);
    ((ushort4*)Wqkv_hi)[i] = h;

    v = ((const float4*)Wk)[i];
    h.x = f2bf(v.x); h.y = f2bf(v.y); h.z = f2bf(v.z); h.w = f2bf(v.w);
    ((ushort4*)Wqkv_hi)[65536 + i] = h;

    v = ((const float4*)Wv)[i];
    h.x = f2bf(v.x); h.y = f2bf(v.y); h.z = f2bf(v.z); h.w = f2bf(v.w);
    ((ushort4*)Wqkv_hi)[131072 + i] = h;

    v = ((const float4*)Wo)[i];
    h.x = f2bf(v.x); h.y = f2bf(v.y); h.z = f2bf(v.z); h.w = f2bf(v.w);
    ((ushort4*)Wo_hi)[i] = h;
    ushort4 lo;
    lo.x = f2bf(v.x - bf2f(h.x)); lo.y = f2bf(v.y - bf2f(h.y));
    lo.z = f2bf(v.z - bf2f(h.z)); lo.w = f2bf(v.w - bf2f(h.w));
    ((ushort4*)Wo_lo)[i] = lo;

    if (i < 512)       bqkv[i] = bq[i];
    else if (i < 1024) bqkv[i] = bk[i - 512];
    else if (i < 1536) bqkv[i] = bv[i - 1024];
}

// ---------------------------------------------------------------------------
// x (B,C,L) fp32 -> xT bf16 (B,L,C).  32x32 LDS transpose.
// ---------------------------------------------------------------------------
__global__ __launch_bounds__(256) void transpose_kernel(
    const float* __restrict__ x, unsigned short* __restrict__ xT)
{
    __shared__ float tile[32][33];
    const int b  = blockIdx.z;
    const int cb = blockIdx.y * 32;
    const int lb = blockIdx.x * 32;
    const int t  = threadIdx.x;
    {
        const int l = t & 31, c0 = t >> 5;
#pragma unroll
        for (int p = 0; p < 4; ++p) {
            const int c = c0 + 8 * p;
            tile[c][l] = x[((size_t)b * C_ + cb + c) * L_ + lb + l];
        }
    }
    __syncthreads();
    {
        const int c = t & 31, l0 = t >> 5;
#pragma unroll
        for (int p = 0; p < 4; ++p) {
            const int l = l0 + 8 * p;
            xT[((size_t)b * L_ + lb + l) * C_ + cb + c] = f2bf(tile[c][l]);
        }
    }
}

// ---------------------------------------------------------------------------
// Fused QKV GEMM, plain bf16.  M=1536 x N=1024 x K=512.
// Q,K: LDS-transposed epilogue -> coalesced (B,H,L,Dh) bf16 (Q pre-scaled).
// V:   direct coalesced (B,C,L) bf16.
// ---------------------------------------------------------------------------
__global__ __launch_bounds__(256) void qkv_gemm_kernel(
    const unsigned short* __restrict__ Wh, const float* __restrict__ bqkv,
    const unsigned short* __restrict__ xT,
    unsigned short* __restrict__ Qb, unsigned short* __restrict__ Kb,
    unsigned short* __restrict__ Vc)
{
    __shared__ __align__(16) unsigned short As[128][40];
    __shared__ __align__(16) unsigned short Bs[128][40];
    __shared__ __align__(16) unsigned short sT[128][66];   // transpose buffer

    const int b   = blockIdx.z;
    const int oB  = blockIdx.y * 128;
    const int mat = oB >> 9;                // 0=Q,1=K,2=V
    const int ob  = oB & 511;
    const int lb  = blockIdx.x * 128;
    const int t  = threadIdx.x;
    const int w = t >> 6, lane = t & 63, quad = lane >> 4, lc = lane & 15;
    const int wm = w >> 1, wn = w & 1;

    const unsigned short* Wm = Wh + (size_t)mat * C_ * C_;

    floatx4 acc[4][4];
#pragma unroll
    for (int i = 0; i < 4; ++i)
#pragma unroll
        for (int j = 0; j < 4; ++j) acc[i][j] = (floatx4)0.f;

    const int c8 = (t & 3) * 8, r0 = t >> 2;
    for (int c0 = 0; c0 < C_; c0 += 32) {
#pragma unroll
        for (int p = 0; p < 2; ++p) {
            *reinterpret_cast<uint4*>(&As[r0 + 64 * p][c8]) =
                *reinterpret_cast<const uint4*>(&Wm[(size_t)(ob + r0 + 64 * p) * C_ + c0 + c8]);
            *reinterpret_cast<uint4*>(&Bs[r0 + 64 * p][c8]) =
                *reinterpret_cast<const uint4*>(&xT[((size_t)b * L_ + lb + r0 + 64 * p) * C_ + c0 + c8]);
        }
        __syncthreads();

        short8 a[4], bb[4];
#pragma unroll
        for (int mt = 0; mt < 4; ++mt)
            a[mt] = *reinterpret_cast<const short8*>(&As[wm * 64 + mt * 16 + lc][quad * 8]);
#pragma unroll
        for (int nt = 0; nt < 4; ++nt)
            bb[nt] = *reinterpret_cast<const short8*>(&Bs[wn * 64 + nt * 16 + lc][quad * 8]);
#pragma unroll
        for (int mt = 0; mt < 4; ++mt)
#pragma unroll
            for (int nt = 0; nt < 4; ++nt)
                acc[mt][nt] = __builtin_amdgcn_mfma_f32_16x16x32_bf16(a[mt], bb[nt], acc[mt][nt], 0, 0, 0);
        __syncthreads();
    }

    if (mat == 2) {
        // V: direct coalesced (B,C,L)
#pragma unroll
        for (int mt = 0; mt < 4; ++mt) {
#pragma unroll
            for (int r = 0; r < 4; ++r) {
                const int o  = ob + wm * 64 + mt * 16 + quad * 4 + r;
                const float bi = bqkv[1024 + o];
#pragma unroll
                for (int nt = 0; nt < 4; ++nt) {
                    const int l = lb + wn * 64 + nt * 16 + lc;
                    Vc[((size_t)b * C_ + o) * L_ + l] = f2bf(acc[mt][nt][r] + bi);
                }
            }
        }
    } else {
        // Q/K: per-head LDS transpose, then coalesced (B,H,L,Dh) stores
        const float scale = (mat == 0) ? 0.125f : 1.0f;
        unsigned short* dst = (mat == 0) ? Qb : Kb;
#pragma unroll
        for (int hh = 0; hh < 2; ++hh) {
            if (wm == hh) {
#pragma unroll
                for (int mt = 0; mt < 4; ++mt) {
#pragma unroll
                    for (int r = 0; r < 4; ++r) {
                        const int o  = ob + hh * 64 + mt * 16 + quad * 4 + r;
                        const float bi = bqkv[mat * 512 + o];
                        const int d  = mt * 16 + quad * 4 + r;
#pragma unroll
                        for (int nt = 0; nt < 4; ++nt) {
                            const int l = wn * 64 + nt * 16 + lc;
                            sT[l][d] = f2bf((acc[mt][nt][r] + bi) * scale);
                        }
                    }
                }
            }
            __syncthreads();
            {
                const int l  = t >> 1, hf = t & 1;
                const int h  = (ob >> 6) + hh;
                const size_t o = (((size_t)b * H_ + h) * L_ + lb + l) * DH + hf * 32;
                uint4 v0 = *reinterpret_cast<const uint4*>(&sT[l][hf * 32]);
                uint4 v1 = *reinterpret_cast<const uint4*>(&sT[l][hf * 32 + 8]);
                uint4 v2 = *reinterpret_cast<const uint4*>(&sT[l][hf * 32 + 16]);
                uint4 v3 = *reinterpret_cast<const uint4*>(&sT[l][hf * 32 + 24]);
                *reinterpret_cast<uint4*>(&dst[o])      = v0;
                *reinterpret_cast<uint4*>(&dst[o + 8])  = v1;
                *reinterpret_cast<uint4*>(&dst[o + 16]) = v2;
                *reinterpret_cast<uint4*>(&dst[o + 24]) = v3;
            }
            __syncthreads();
        }
    }
}

// ---------------------------------------------------------------------------
// Attention v7: R6 structure (128 q-rows/block, proven best) + LDS diet to
// 52.7 KB -> 3 blocks/CU (12 waves vs R6's 5.6 avg) + conflict-free pads (68)
// + vectorized single-bf16 AO epilogue (full-line dwordx4 stores; kills the
// 50MB->16MB write amplification measured in R8).
// grid (bh 64, rt 8) = 512 blocks; id%8==h -> XCD L2 locality.
// 4 waves x 32 rows (2 row-groups reuse each K/V fragment).
// ---------------------------------------------------------------------------
__global__ __launch_bounds__(256, 3) void attn_kernel7(
    const unsigned short* __restrict__ Qb,   // bf16 (B,H,L,Dh), pre-scaled
    const unsigned short* __restrict__ Kb,   // bf16 (B,H,L,Dh)
    const unsigned short* __restrict__ Vc,   // bf16 (B,C,L)
    const float* __restrict__ erel_k, const float* __restrict__ erel_v,
    unsigned short* __restrict__ AOh)
{
    __shared__ __align__(16) unsigned short kst[2][64][68];  // [buf][j][d]
    __shared__ __align__(16) unsigned short vst[2][64][68];  // [buf][d][j]
    __shared__ __align__(16) unsigned short Pl[4][16][68];   // per-wave P (reused per rg)
    __shared__ float rs[128][9];
    __shared__ float rv[128][9];

    const int t  = threadIdx.x;
    const int bh = blockIdx.x;          // 0..63
    const int rt = blockIdx.y;          // 0..7
    const int b = bh >> 3, h = bh & 7;
    const int w = t >> 6, lane = t & 63, quad = lane >> 4, lc = lane & 15;
    const int row0 = rt * 128;
    const int rowW = row0 + w * 32;

    const size_t qkBase = (size_t)bh * L_ * DH;
    const size_t vBase  = ((size_t)b * C_ + h * DH) * L_;

    for (int i = lane; i < 32 * 9; i += 64) rv[w * 32 + i / 9][i % 9] = 0.f;

    // Q A-fragments (2 row-groups of 16), reused across all 16 tiles
    short8 af[2][2];
#pragma unroll
    for (int rg = 0; rg < 2; ++rg)
#pragma unroll
        for (int kk = 0; kk < 2; ++kk)
            af[rg][kk] = *reinterpret_cast<const short8*>(
                &Qb[qkBase + (size_t)(rowW + rg * 16 + lc) * DH + kk * 32 + quad * 8]);

    // rel-k scores via MFMA: B[n=dr][k=d] = erk[dr][d]
#pragma unroll
    for (int rg = 0; rg < 2; ++rg) {
        floatx4 rsa = (floatx4)0.f;
        const int drow = (lc < 9) ? lc : 8;
#pragma unroll
        for (int kk = 0; kk < 2; ++kk) {
            short8 bfr;
#pragma unroll
            for (int i = 0; i < 8; ++i)
                bfr[i] = (short)f2bf(erel_k[drow * 64 + kk * 32 + quad * 8 + i]);
            rsa = __builtin_amdgcn_mfma_f32_16x16x32_bf16(af[rg][kk], bfr, rsa, 0, 0, 0);
        }
        if (lc < 9) {
#pragma unroll
            for (int r = 0; r < 4; ++r)
                rs[w * 32 + rg * 16 + quad * 4 + r][lc] = rsa[r];
        }
    }

    // stage tile 0
    const int jr = t >> 3, jc = (t & 7) * 8;
#pragma unroll
    for (int p = 0; p < 2; ++p) {
        *reinterpret_cast<uint4*>(&kst[0][jr + 32 * p][jc]) =
            *reinterpret_cast<const uint4*>(&Kb[qkBase + (size_t)(jr + 32 * p) * DH + jc]);
        *reinterpret_cast<uint4*>(&vst[0][jr + 32 * p][jc]) =
            *reinterpret_cast<const uint4*>(&Vc[vBase + (size_t)(jr + 32 * p) * L_ + jc]);
    }
    __syncthreads();

    short8 ones;
#pragma unroll
    for (int j = 0; j < 8; ++j) ones[j] = (short)0x3F80;

    floatx4 acc_o[2][4], acc_l[2];
#pragma unroll
    for (int rg = 0; rg < 2; ++rg) {
        acc_l[rg] = (floatx4)0.f;
#pragma unroll
        for (int nt = 0; nt < 4; ++nt) acc_o[rg][nt] = (floatx4)0.f;
    }

    for (int jt = 0; jt < L_ / 64; ++jt) {
        const int j0  = jt * 64;
        const int cur = jt & 1;

        // register prefetch of next tile (hidden under compute)
        uint4 pk[2], pv[2];
        if (jt < L_ / 64 - 1) {
            const int j0n = j0 + 64;
#pragma unroll
            for (int p = 0; p < 2; ++p) {
                pk[p] = *reinterpret_cast<const uint4*>(
                    &Kb[qkBase + (size_t)(j0n + jr + 32 * p) * DH + jc]);
                pv[p] = *reinterpret_cast<const uint4*>(
                    &Vc[vBase + (size_t)(jr + 32 * p) * L_ + j0n + jc]);
            }
        }

        // K fragments (shared by both row-groups)
        short8 kf[4][2];
#pragma unroll
        for (int nt = 0; nt < 4; ++nt)
#pragma unroll
            for (int kk = 0; kk < 2; ++kk)
                kf[nt][kk] = *reinterpret_cast<const short8*>(
                    &kst[cur][nt * 16 + lc][kk * 32 + quad * 8]);

#pragma unroll
        for (int rg = 0; rg < 2; ++rg) {
            const int rowWg = rowW + rg * 16;

            // S = Q K^T
            floatx4 sacc[4];
#pragma unroll
            for (int nt = 0; nt < 4; ++nt) sacc[nt] = (floatx4)0.f;
#pragma unroll
            for (int nt = 0; nt < 4; ++nt)
#pragma unroll
                for (int kk = 0; kk < 2; ++kk)
                    sacc[nt] = __builtin_amdgcn_mfma_f32_16x16x32_bf16(
                        af[rg][kk], kf[nt][kk], sacc[nt], 0, 0, 0);

            // windowed rel-k bias (near-diagonal tiles only)
            const bool nearD = (j0 <= rowWg + 15 + WIN) && (j0 + 63 >= rowWg - WIN);
            if (nearD) {
#pragma unroll
                for (int nt = 0; nt < 4; ++nt) {
                    const int jg = j0 + nt * 16 + lc;
#pragma unroll
                    for (int r = 0; r < 4; ++r) {
                        const int diff = jg - (rowWg + quad * 4 + r);
                        if (diff >= -WIN && diff <= WIN)
                            sacc[nt][r] += rs[w * 32 + rg * 16 + quad * 4 + r][diff + WIN];
                    }
                }
            }

            // exp (no max subtraction; scores bounded ~|6|), P -> LDS bf16
#pragma unroll
            for (int nt = 0; nt < 4; ++nt)
#pragma unroll
                for (int r = 0; r < 4; ++r)
                    Pl[w][quad * 4 + r][nt * 16 + lc] = f2bf(__expf(sacc[nt][r]));

            // rel-v prob accumulation (gated; wave-private rows, in-order DS)
            if (nearD) {
                for (int idx = lane; idx < 16 * 9; idx += 64) {
                    const int r16 = idx / 9, dr = idx % 9;
                    const int jg = rowWg + r16 + dr - WIN;
                    if (jg >= j0 && jg < j0 + 64 && jg >= 0 && jg < L_)
                        rv[w * 32 + rg * 16 + r16][dr] += bf2f(Pl[w][r16][jg - j0]);
                }
            }

            // P back as A-fragments
            short8 pf[2];
#pragma unroll
            for (int kk = 0; kk < 2; ++kk)
                pf[kk] = *reinterpret_cast<const short8*>(&Pl[w][lc][kk * 32 + quad * 8]);

            // row sums via MFMA
#pragma unroll
            for (int kk = 0; kk < 2; ++kk)
                acc_l[rg] = __builtin_amdgcn_mfma_f32_16x16x32_bf16(
                    pf[kk], ones, acc_l[rg], 0, 0, 0);

            // O += P V  (V B-frags from LDS)
#pragma unroll
            for (int nt = 0; nt < 4; ++nt)
#pragma unroll
                for (int kk = 0; kk < 2; ++kk) {
                    const short8 vf = *reinterpret_cast<const short8*>(
                        &vst[cur][nt * 16 + lc][kk * 32 + quad * 8]);
                    acc_o[rg][nt] = __builtin_amdgcn_mfma_f32_16x16x32_bf16(
                        pf[kk], vf, acc_o[rg][nt], 0, 0, 0);
                }
        }

        // commit prefetched tile, then sync
        if (jt < L_ / 64 - 1) {
#pragma unroll
            for (int p = 0; p < 2; ++p) {
                *reinterpret_cast<uint4*>(&kst[1 - cur][jr + 32 * p][jc]) = pk[p];
                *reinterpret_cast<uint4*>(&vst[1 - cur][jr + 32 * p][jc]) = pv[p];
            }
        }
        __syncthreads();
    }

    // epilogue: rel-v term, normalize, transpose via Pl, full-line stores
#pragma unroll
    for (int rg = 0; rg < 2; ++rg) {
#pragma unroll
        for (int nt = 0; nt < 4; ++nt) {
            const int d = nt * 16 + lc;
            float ev[9];
#pragma unroll
            for (int dr = 0; dr < 9; ++dr) ev[dr] = erel_v[dr * 64 + d];
#pragma unroll
            for (int r = 0; r < 4; ++r) {
                const int rloc = w * 32 + rg * 16 + quad * 4 + r;
                float v = acc_o[rg][nt][r];
#pragma unroll
                for (int dr = 0; dr < 9; ++dr) v += rv[rloc][dr] * ev[dr];
                Pl[w][quad * 4 + r][nt * 16 + lc] = f2bf(v / acc_l[rg][r]);
            }
        }
        // same-wave in-order DS: read transposed rows, store 128B lines
        {
            const int row = lane >> 2, ds8 = (lane & 3) * 16;
            const uint4 q0 = *reinterpret_cast<const uint4*>(&Pl[w][row][ds8]);
            const uint4 q1 = *reinterpret_cast<const uint4*>(&Pl[w][row][ds8 + 8]);
            const size_t o =
                ((size_t)b * L_ + row0 + w * 32 + rg * 16 + row) * C_ + h * 64 + ds8;
            *reinterpret_cast<uint4*>(&AOh[o])     = q0;
            *reinterpret_cast<uint4*>(&AOh[o + 8]) = q1;
        }
    }
}

// ---------------------------------------------------------------------------
// Output projection, 2-term (Wh+Wl)·AOh.  M=512 x N-tile 64 x K=512.
// ---------------------------------------------------------------------------
__global__ __launch_bounds__(256) void out_gemm_kernel(
    const unsigned short* __restrict__ Wh, const unsigned short* __restrict__ Wl,
    const float* __restrict__ bo,
    const unsigned short* __restrict__ Ah,
    float* __restrict__ Y)
{
    __shared__ __align__(16) unsigned short As_h[128][40];
    __shared__ __align__(16) unsigned short As_l[128][40];
    __shared__ __align__(16) unsigned short Bs_h[64][40];

    const int b  = blockIdx.z;
    const int ob = blockIdx.y * 128;
    const int lb = blockIdx.x * 64;
    const int t  = threadIdx.x;
    const int w = t >> 6, lane = t & 63, quad = lane >> 4, lc = lane & 15;
    const int wm = w >> 1, wn = w & 1;

    floatx4 acc[4][2];
#pragma unroll
    for (int i = 0; i < 4; ++i)
#pragma unroll
        for (int j = 0; j < 2; ++j) acc[i][j] = (floatx4)0.f;

    const int c8 = (t & 3) * 8, r0 = t >> 2;
    for (int c0 = 0; c0 < C_; c0 += 32) {
#pragma unroll
        for (int p = 0; p < 2; ++p) {
            *reinterpret_cast<uint4*>(&As_h[r0 + 64 * p][c8]) =
                *reinterpret_cast<const uint4*>(&Wh[(size_t)(ob + r0 + 64 * p) * C_ + c0 + c8]);
            *reinterpret_cast<uint4*>(&As_l[r0 + 64 * p][c8]) =
                *reinterpret_cast<const uint4*>(&Wl[(size_t)(ob + r0 + 64 * p) * C_ + c0 + c8]);
        }
        {
            const size_t g = ((size_t)b * L_ + lb + r0) * C_ + c0 + c8;
            *reinterpret_cast<uint4*>(&Bs_h[r0][c8]) =
                *reinterpret_cast<const uint4*>(&Ah[g]);
        }
        __syncthreads();

        short8 ah[4], al[4], bhf[2];
#pragma unroll
        for (int mt = 0; mt < 4; ++mt) {
            const int row = wm * 64 + mt * 16 + lc;
            ah[mt] = *reinterpret_cast<const short8*>(&As_h[row][quad * 8]);
            al[mt] = *reinterpret_cast<const short8*>(&As_l[row][quad * 8]);
        }
#pragma unroll
        for (int nt = 0; nt < 2; ++nt) {
            const int row = wn * 32 + nt * 16 + lc;
            bhf[nt] = *reinterpret_cast<const short8*>(&Bs_h[row][quad * 8]);
        }
#pragma unroll
        for (int mt = 0; mt < 4; ++mt)
#pragma unroll
            for (int nt = 0; nt < 2; ++nt) {
                acc[mt][nt] = __builtin_amdgcn_mfma_f32_16x16x32_bf16(ah[mt], bhf[nt], acc[mt][nt], 0, 0, 0);
                acc[mt][nt] = __builtin_amdgcn_mfma_f32_16x16x32_bf16(al[mt], bhf[nt], acc[mt][nt], 0, 0, 0);
            }
        __syncthreads();
    }

#pragma unroll
    for (int mt = 0; mt < 4; ++mt) {
#pragma unroll
        for (int r = 0; r < 4; ++r) {
            const int o = ob + wm * 64 + mt * 16 + quad * 4 + r;
            const float bi = bo[o];
#pragma unroll
            for (int nt = 0; nt < 2; ++nt) {
                const int l = lb + wn * 32 + nt * 16 + lc;
                Y[((size_t)b * C_ + o) * L_ + l] = acc[mt][nt][r] + bi;
            }
        }
    }
}

// ---------------------------------------------------------------------------
extern "C" void kernel_launch(void* const* d_in, const int* in_sizes, int n_in,
                              void* d_out, int out_size, void* d_ws, size_t ws_size,
                              hipStream_t stream)
{
    const float* x   = (const float*)d_in[0];
    const float* Wq  = (const float*)d_in[1];
    const float* bq  = (const float*)d_in[2];
    const float* Wk  = (const float*)d_in[3];
    const float* bk  = (const float*)d_in[4];
    const float* Wv  = (const float*)d_in[5];
    const float* bv  = (const float*)d_in[6];
    const float* Wo  = (const float*)d_in[7];
    const float* bo  = (const float*)d_in[8];
    const float* erk = (const float*)d_in[9];
    const float* erv = (const float*)d_in[10];

    char* ws = (char*)d_ws;
    const size_t MB = 1024u * 1024u;
    unsigned short* xT      = (unsigned short*)(ws);             // 8 MB
    unsigned short* Qb      = (unsigned short*)(ws + 8 * MB);    // 8 MB (B,H,L,Dh)
    unsigned short* Kb      = (unsigned short*)(ws + 16 * MB);   // 8 MB (B,H,L,Dh)
    unsigned short* Vc      = (unsigned short*)(ws + 24 * MB);   // 8 MB (B,C,L)
    unsigned short* AOh     = (unsigned short*)(ws + 32 * MB);   // 8 MB (B,L,C)
    unsigned short* Wqkv_hi = (unsigned short*)(ws + 40 * MB);   // 1.5 MB
    unsigned short* Wo_hi   = (unsigned short*)(ws + 42 * MB);   // 0.5 MB
    unsigned short* Wo_lo   = (unsigned short*)(ws + 43 * MB);   // 0.5 MB
    float*          bqkv    = (float*)(ws + 44 * MB);            // 6 KB

    prep_kernel<<<256, 256, 0, stream>>>(Wq, Wk, Wv, Wo, bq, bk, bv,
                                         Wqkv_hi, Wo_hi, Wo_lo, bqkv);
    transpose_kernel<<<dim3(L_ / 32, C_ / 32, B_), 256, 0, stream>>>(x, xT);
    qkv_gemm_kernel<<<dim3(L_ / 128, 12, B_), 256, 0, stream>>>(
        Wqkv_hi, bqkv, xT, Qb, Kb, Vc);
    attn_kernel7<<<dim3(64, 8), 256, 0, stream>>>(
        Qb, Kb, Vc, erk, erv, AOh);
    out_gemm_kernel<<<dim3(L_ / 64, C_ / 128, B_), 256, 0, stream>>>(
        Wo_hi, Wo_lo, bo, AOh, (float*)d_out);
}

// Round 10
// 187.773 us; speedup vs baseline: 1.2440x; 1.0967x over previous
//
#include <hip/hip_runtime.h>
#include <math.h>

#define B_  8
#define H_  8
#define C_  512
#define L_  1024
#define DH  64
#define WIN 4

typedef __attribute__((ext_vector_type(8))) short short8;
typedef __attribute__((ext_vector_type(4))) float floatx4;

__device__ __forceinline__ unsigned short f2bf(float f) {
    unsigned int u = __float_as_uint(f);
    u = u + 0x7FFFu + ((u >> 16) & 1u);     // RNE
    return (unsigned short)(u >> 16);
}
__device__ __forceinline__ float bf2f(unsigned short h) {
    return __uint_as_float(((unsigned int)h) << 16);
}
__device__ __forceinline__ unsigned short f2h(float f) {
    _Float16 h = (_Float16)f;
    return *reinterpret_cast<unsigned short*>(&h);
}

// ---------------------------------------------------------------------------
// prep: Wq/Wk/Wv -> bf16 (packed 3x512x512), Wo -> f16, pack biases.
// ---------------------------------------------------------------------------
__global__ __launch_bounds__(256) void prep_kernel(
    const float* __restrict__ Wq, const float* __restrict__ Wk,
    const float* __restrict__ Wv, const float* __restrict__ Wo,
    const float* __restrict__ bq, const float* __restrict__ bk,
    const float* __restrict__ bv,
    unsigned short* __restrict__ Wqkv_hi,
    unsigned short* __restrict__ Wo_h,
    float* __restrict__ bqkv)
{
    const int i = blockIdx.x * 256 + threadIdx.x;   // 65536 float4 slots
    float4 v; ushort4 h;

    v = ((const float4*)Wq)[i];
    h.x = f2bf(v.x); h.y = f2bf(v.y); h.z = f2bf(v.z); h.w = f2bf(v.w);
    ((ushort4*)Wqkv_hi)[i] = h;

    v = ((const float4*)Wk)[i];
    h.x = f2bf(v.x); h.y = f2bf(v.y); h.z = f2bf(v.z); h.w = f2bf(v.w);
    ((ushort4*)Wqkv_hi)[65536 + i] = h;

    v = ((const float4*)Wv)[i];
    h.x = f2bf(v.x); h.y = f2bf(v.y); h.z = f2bf(v.z); h.w = f2bf(v.w);
    ((ushort4*)Wqkv_hi)[131072 + i] = h;

    v = ((const float4*)Wo)[i];
    h.x = f2h(v.x); h.y = f2h(v.y); h.z = f2h(v.z); h.w = f2h(v.w);
    ((ushort4*)Wo_h)[i] = h;

    if (i < 512)       bqkv[i] = bq[i];
    else if (i < 1024) bqkv[i] = bk[i - 512];
    else if (i < 1536) bqkv[i] = bv[i - 1024];
}

// ---------------------------------------------------------------------------
// x (B,C,L) fp32 -> xT bf16 (B,L,C).  32x32 LDS transpose.
// ---------------------------------------------------------------------------
__global__ __launch_bounds__(256) void transpose_kernel(
    const float* __restrict__ x, unsigned short* __restrict__ xT)
{
    __shared__ float tile[32][33];
    const int b  = blockIdx.z;
    const int cb = blockIdx.y * 32;
    const int lb = blockIdx.x * 32;
    const int t  = threadIdx.x;
    {
        const int l = t & 31, c0 = t >> 5;
#pragma unroll
        for (int p = 0; p < 4; ++p) {
            const int c = c0 + 8 * p;
            tile[c][l] = x[((size_t)b * C_ + cb + c) * L_ + lb + l];
        }
    }
    __syncthreads();
    {
        const int c = t & 31, l0 = t >> 5;
#pragma unroll
        for (int p = 0; p < 4; ++p) {
            const int l = l0 + 8 * p;
            xT[((size_t)b * L_ + lb + l) * C_ + cb + c] = f2bf(tile[c][l]);
        }
    }
}

// ---------------------------------------------------------------------------
// Fused QKV GEMM, plain bf16.  M=1536 x N=1024 x K=512.
// Q,K: LDS-transposed epilogue -> coalesced (B,H,L,Dh) bf16 (Q pre-scaled).
// V:   direct coalesced (B,C,L) bf16.
// ---------------------------------------------------------------------------
__global__ __launch_bounds__(256) void qkv_gemm_kernel(
    const unsigned short* __restrict__ Wh, const float* __restrict__ bqkv,
    const unsigned short* __restrict__ xT,
    unsigned short* __restrict__ Qb, unsigned short* __restrict__ Kb,
    unsigned short* __restrict__ Vc)
{
    __shared__ __align__(16) unsigned short As[128][40];
    __shared__ __align__(16) unsigned short Bs[128][40];
    __shared__ __align__(16) unsigned short sT[128][66];   // transpose buffer

    const int b   = blockIdx.z;
    const int oB  = blockIdx.y * 128;
    const int mat = oB >> 9;                // 0=Q,1=K,2=V
    const int ob  = oB & 511;
    const int lb  = blockIdx.x * 128;
    const int t  = threadIdx.x;
    const int w = t >> 6, lane = t & 63, quad = lane >> 4, lc = lane & 15;
    const int wm = w >> 1, wn = w & 1;

    const unsigned short* Wm = Wh + (size_t)mat * C_ * C_;

    floatx4 acc[4][4];
#pragma unroll
    for (int i = 0; i < 4; ++i)
#pragma unroll
        for (int j = 0; j < 4; ++j) acc[i][j] = (floatx4)0.f;

    const int c8 = (t & 3) * 8, r0 = t >> 2;
    for (int c0 = 0; c0 < C_; c0 += 32) {
#pragma unroll
        for (int p = 0; p < 2; ++p) {
            *reinterpret_cast<uint4*>(&As[r0 + 64 * p][c8]) =
                *reinterpret_cast<const uint4*>(&Wm[(size_t)(ob + r0 + 64 * p) * C_ + c0 + c8]);
            *reinterpret_cast<uint4*>(&Bs[r0 + 64 * p][c8]) =
                *reinterpret_cast<const uint4*>(&xT[((size_t)b * L_ + lb + r0 + 64 * p) * C_ + c0 + c8]);
        }
        __syncthreads();

        short8 a[4], bb[4];
#pragma unroll
        for (int mt = 0; mt < 4; ++mt)
            a[mt] = *reinterpret_cast<const short8*>(&As[wm * 64 + mt * 16 + lc][quad * 8]);
#pragma unroll
        for (int nt = 0; nt < 4; ++nt)
            bb[nt] = *reinterpret_cast<const short8*>(&Bs[wn * 64 + nt * 16 + lc][quad * 8]);
#pragma unroll
        for (int mt = 0; mt < 4; ++mt)
#pragma unroll
            for (int nt = 0; nt < 4; ++nt)
                acc[mt][nt] = __builtin_amdgcn_mfma_f32_16x16x32_bf16(a[mt], bb[nt], acc[mt][nt], 0, 0, 0);
        __syncthreads();
    }

    if (mat == 2) {
        // V: direct coalesced (B,C,L)
#pragma unroll
        for (int mt = 0; mt < 4; ++mt) {
#pragma unroll
            for (int r = 0; r < 4; ++r) {
                const int o  = ob + wm * 64 + mt * 16 + quad * 4 + r;
                const float bi = bqkv[1024 + o];
#pragma unroll
                for (int nt = 0; nt < 4; ++nt) {
                    const int l = lb + wn * 64 + nt * 16 + lc;
                    Vc[((size_t)b * C_ + o) * L_ + l] = f2bf(acc[mt][nt][r] + bi);
                }
            }
        }
    } else {
        // Q/K: per-head LDS transpose, then coalesced (B,H,L,Dh) stores
        const float scale = (mat == 0) ? 0.125f : 1.0f;
        unsigned short* dst = (mat == 0) ? Qb : Kb;
#pragma unroll
        for (int hh = 0; hh < 2; ++hh) {
            if (wm == hh) {
#pragma unroll
                for (int mt = 0; mt < 4; ++mt) {
#pragma unroll
                    for (int r = 0; r < 4; ++r) {
                        const int o  = ob + hh * 64 + mt * 16 + quad * 4 + r;
                        const float bi = bqkv[mat * 512 + o];
                        const int d  = mt * 16 + quad * 4 + r;
#pragma unroll
                        for (int nt = 0; nt < 4; ++nt) {
                            const int l = wn * 64 + nt * 16 + lc;
                            sT[l][d] = f2bf((acc[mt][nt][r] + bi) * scale);
                        }
                    }
                }
            }
            __syncthreads();
            {
                const int l  = t >> 1, hf = t & 1;
                const int h  = (ob >> 6) + hh;
                const size_t o = (((size_t)b * H_ + h) * L_ + lb + l) * DH + hf * 32;
                uint4 v0 = *reinterpret_cast<const uint4*>(&sT[l][hf * 32]);
                uint4 v1 = *reinterpret_cast<const uint4*>(&sT[l][hf * 32 + 8]);
                uint4 v2 = *reinterpret_cast<const uint4*>(&sT[l][hf * 32 + 16]);
                uint4 v3 = *reinterpret_cast<const uint4*>(&sT[l][hf * 32 + 24]);
                *reinterpret_cast<uint4*>(&dst[o])      = v0;
                *reinterpret_cast<uint4*>(&dst[o + 8])  = v1;
                *reinterpret_cast<uint4*>(&dst[o + 16]) = v2;
                *reinterpret_cast<uint4*>(&dst[o + 24]) = v3;
            }
            __syncthreads();
        }
    }
}

// ---------------------------------------------------------------------------
// Attention v8: R9 structure, 512-thread blocks.
// grid (bh 64, rt 8) = 512 blocks; 8 waves x 16 q-rows = 128 rows/block
// (same staging amortization as R9) but 16 waves/CU (2 blocks x 8) vs 8:
// LDS = kst+vst+Pl[8]+rs+rv = exactly 60.0 KB -> 2 blocks/CU.
// K/V double-buffered LDS, one barrier/tile, pads 68 (conflict-free, R9-
// verified: 86K conflict cycles).  AO emitted as f16 (B,L,C) for the 1-term
// f16 output projection.
// ---------------------------------------------------------------------------
__global__ __launch_bounds__(512, 4) void attn_kernel8(
    const unsigned short* __restrict__ Qb,   // bf16 (B,H,L,Dh), pre-scaled
    const unsigned short* __restrict__ Kb,   // bf16 (B,H,L,Dh)
    const unsigned short* __restrict__ Vc,   // bf16 (B,C,L)
    const float* __restrict__ erel_k, const float* __restrict__ erel_v,
    unsigned short* __restrict__ AOh)        // f16 (B,L,C)
{
    __shared__ __align__(16) unsigned short kst[2][64][68];  // [buf][j][d]
    __shared__ __align__(16) unsigned short vst[2][64][68];  // [buf][d][j]
    __shared__ __align__(16) unsigned short Pl[8][16][68];   // per-wave P
    __shared__ float rs[128][9];
    __shared__ float rv[128][9];

    const int t  = threadIdx.x;
    const int bh = blockIdx.x;          // 0..63  (id%8==h -> XCD L2 locality)
    const int rt = blockIdx.y;          // 0..7
    const int b = bh >> 3, h = bh & 7;
    const int w = t >> 6, lane = t & 63, quad = lane >> 4, lc = lane & 15;
    const int row0 = rt * 128;
    const int rowW = row0 + w * 16;     // wave's 16 rows

    const size_t qkBase = (size_t)bh * L_ * DH;
    const size_t vBase  = ((size_t)b * C_ + h * DH) * L_;

    for (int i = lane; i < 16 * 9; i += 64) rv[w * 16 + i / 9][i % 9] = 0.f;

    // Q A-fragments (16 rows), reused across all 16 key tiles
    short8 af[2];
#pragma unroll
    for (int kk = 0; kk < 2; ++kk)
        af[kk] = *reinterpret_cast<const short8*>(
            &Qb[qkBase + (size_t)(rowW + lc) * DH + kk * 32 + quad * 8]);

    // rel-k scores via MFMA: B[n=dr][k=d] = erk[dr][d]
    {
        floatx4 rsa = (floatx4)0.f;
        const int drow = (lc < 9) ? lc : 8;
#pragma unroll
        for (int kk = 0; kk < 2; ++kk) {
            short8 bfr;
#pragma unroll
            for (int i = 0; i < 8; ++i)
                bfr[i] = (short)f2bf(erel_k[drow * 64 + kk * 32 + quad * 8 + i]);
            rsa = __builtin_amdgcn_mfma_f32_16x16x32_bf16(af[kk], bfr, rsa, 0, 0, 0);
        }
        if (lc < 9) {
#pragma unroll
            for (int r = 0; r < 4; ++r)
                rs[w * 16 + quad * 4 + r][lc] = rsa[r];
        }
    }

    // stage tile 0 (512 thr: one uint4 per thread per array covers 64x64)
    const int jr = t >> 3, jc = (t & 7) * 8;
    *reinterpret_cast<uint4*>(&kst[0][jr][jc]) =
        *reinterpret_cast<const uint4*>(&Kb[qkBase + (size_t)jr * DH + jc]);
    *reinterpret_cast<uint4*>(&vst[0][jr][jc]) =
        *reinterpret_cast<const uint4*>(&Vc[vBase + (size_t)jr * L_ + jc]);
    __syncthreads();

    short8 ones;
#pragma unroll
    for (int j = 0; j < 8; ++j) ones[j] = (short)0x3F80;

    floatx4 acc_o[4], acc_l = (floatx4)0.f;
#pragma unroll
    for (int nt = 0; nt < 4; ++nt) acc_o[nt] = (floatx4)0.f;

    for (int jt = 0; jt < L_ / 64; ++jt) {
        const int j0  = jt * 64;
        const int cur = jt & 1;

        // register prefetch of next tile
        uint4 pk, pv;
        if (jt < L_ / 64 - 1) {
            const int j0n = j0 + 64;
            pk = *reinterpret_cast<const uint4*>(
                &Kb[qkBase + (size_t)(j0n + jr) * DH + jc]);
            pv = *reinterpret_cast<const uint4*>(
                &Vc[vBase + (size_t)jr * L_ + j0n + jc]);
        }

        // S = Q K^T
        floatx4 sacc[4];
#pragma unroll
        for (int nt = 0; nt < 4; ++nt) sacc[nt] = (floatx4)0.f;
#pragma unroll
        for (int nt = 0; nt < 4; ++nt)
#pragma unroll
            for (int kk = 0; kk < 2; ++kk) {
                const short8 kf = *reinterpret_cast<const short8*>(
                    &kst[cur][nt * 16 + lc][kk * 32 + quad * 8]);
                sacc[nt] = __builtin_amdgcn_mfma_f32_16x16x32_bf16(af[kk], kf, sacc[nt], 0, 0, 0);
            }

        // windowed rel-k bias (near-diagonal tiles only)
        const bool nearD = (j0 <= rowW + 15 + WIN) && (j0 + 63 >= rowW - WIN);
        if (nearD) {
#pragma unroll
            for (int nt = 0; nt < 4; ++nt) {
                const int jg = j0 + nt * 16 + lc;
#pragma unroll
                for (int r = 0; r < 4; ++r) {
                    const int diff = jg - (rowW + quad * 4 + r);
                    if (diff >= -WIN && diff <= WIN)
                        sacc[nt][r] += rs[w * 16 + quad * 4 + r][diff + WIN];
                }
            }
        }

        // exp (no max subtraction; scores bounded ~|6|), P -> LDS bf16
#pragma unroll
        for (int nt = 0; nt < 4; ++nt)
#pragma unroll
            for (int r = 0; r < 4; ++r)
                Pl[w][quad * 4 + r][nt * 16 + lc] = f2bf(__expf(sacc[nt][r]));

        // rel-v prob accumulation (gated; wave-private rows, in-order DS)
        if (nearD) {
            for (int idx = lane; idx < 16 * 9; idx += 64) {
                const int r16 = idx / 9, dr = idx % 9;
                const int jg = rowW + r16 + dr - WIN;
                if (jg >= j0 && jg < j0 + 64 && jg >= 0 && jg < L_)
                    rv[w * 16 + r16][dr] += bf2f(Pl[w][r16][jg - j0]);
            }
        }

        // P back as A-fragments
        short8 pf[2];
#pragma unroll
        for (int kk = 0; kk < 2; ++kk)
            pf[kk] = *reinterpret_cast<const short8*>(&Pl[w][lc][kk * 32 + quad * 8]);

        // row sums via MFMA
#pragma unroll
        for (int kk = 0; kk < 2; ++kk)
            acc_l = __builtin_amdgcn_mfma_f32_16x16x32_bf16(pf[kk], ones, acc_l, 0, 0, 0);

        // O += P V  (V B-frags from LDS)
#pragma unroll
        for (int nt = 0; nt < 4; ++nt)
#pragma unroll
            for (int kk = 0; kk < 2; ++kk) {
                const short8 vf = *reinterpret_cast<const short8*>(
                    &vst[cur][nt * 16 + lc][kk * 32 + quad * 8]);
                acc_o[nt] = __builtin_amdgcn_mfma_f32_16x16x32_bf16(pf[kk], vf, acc_o[nt], 0, 0, 0);
            }

        // commit prefetched tile, then sync
        if (jt < L_ / 64 - 1) {
            *reinterpret_cast<uint4*>(&kst[1 - cur][jr][jc]) = pk;
            *reinterpret_cast<uint4*>(&vst[1 - cur][jr][jc]) = pv;
        }
        __syncthreads();
    }

    // epilogue: rel-v term, normalize, transpose via Pl, full-line f16 stores
#pragma unroll
    for (int nt = 0; nt < 4; ++nt) {
        const int d = nt * 16 + lc;
        float ev[9];
#pragma unroll
        for (int dr = 0; dr < 9; ++dr) ev[dr] = erel_v[dr * 64 + d];
#pragma unroll
        for (int r = 0; r < 4; ++r) {
            const int rloc = w * 16 + quad * 4 + r;
            float v = acc_o[nt][r];
#pragma unroll
            for (int dr = 0; dr < 9; ++dr) v += rv[rloc][dr] * ev[dr];
            Pl[w][quad * 4 + r][nt * 16 + lc] = f2h(v / acc_l[r]);
        }
    }
    {
        const int row = lane >> 2, ds8 = (lane & 3) * 16;
        const uint4 q0 = *reinterpret_cast<const uint4*>(&Pl[w][row][ds8]);
        const uint4 q1 = *reinterpret_cast<const uint4*>(&Pl[w][row][ds8 + 8]);
        const size_t o = ((size_t)b * L_ + rowW + row) * C_ + h * 64 + ds8;
        *reinterpret_cast<uint4*>(&AOh[o])     = q0;
        *reinterpret_cast<uint4*>(&AOh[o + 8]) = q1;
    }
}

// ---------------------------------------------------------------------------
// Output projection, 1-term f16.  M=512 x N-tile 64 x K=512.
// A = Wo f16, B = AO f16 (B,L,C).  Y fp32 (B,C,L).
// ---------------------------------------------------------------------------
__global__ __launch_bounds__(256) void out_gemm_kernel(
    const unsigned short* __restrict__ Wh,
    const float* __restrict__ bo,
    const unsigned short* __restrict__ Ah,
    float* __restrict__ Y)
{
    __shared__ __align__(16) unsigned short As_h[128][40];
    __shared__ __align__(16) unsigned short Bs_h[64][40];

    const int b  = blockIdx.z;
    const int ob = blockIdx.y * 128;
    const int lb = blockIdx.x * 64;
    const int t  = threadIdx.x;
    const int w = t >> 6, lane = t & 63, quad = lane >> 4, lc = lane & 15;
    const int wm = w >> 1, wn = w & 1;

    floatx4 acc[4][2];
#pragma unroll
    for (int i = 0; i < 4; ++i)
#pragma unroll
        for (int j = 0; j < 2; ++j) acc[i][j] = (floatx4)0.f;

    const int c8 = (t & 3) * 8, r0 = t >> 2;
    for (int c0 = 0; c0 < C_; c0 += 32) {
#pragma unroll
        for (int p = 0; p < 2; ++p)
            *reinterpret_cast<uint4*>(&As_h[r0 + 64 * p][c8]) =
                *reinterpret_cast<const uint4*>(&Wh[(size_t)(ob + r0 + 64 * p) * C_ + c0 + c8]);
        {
            const size_t g = ((size_t)b * L_ + lb + r0) * C_ + c0 + c8;
            *reinterpret_cast<uint4*>(&Bs_h[r0][c8]) =
                *reinterpret_cast<const uint4*>(&Ah[g]);
        }
        __syncthreads();

        short8 ah[4], bhf[2];
#pragma unroll
        for (int mt = 0; mt < 4; ++mt)
            ah[mt] = *reinterpret_cast<const short8*>(&As_h[wm * 64 + mt * 16 + lc][quad * 8]);
#pragma unroll
        for (int nt = 0; nt < 2; ++nt)
            bhf[nt] = *reinterpret_cast<const short8*>(&Bs_h[wn * 32 + nt * 16 + lc][quad * 8]);
#pragma unroll
        for (int mt = 0; mt < 4; ++mt)
#pragma unroll
            for (int nt = 0; nt < 2; ++nt)
                acc[mt][nt] = __builtin_amdgcn_mfma_f32_16x16x32_f16(ah[mt], bhf[nt], acc[mt][nt], 0, 0, 0);
        __syncthreads();
    }

#pragma unroll
    for (int mt = 0; mt < 4; ++mt) {
#pragma unroll
        for (int r = 0; r < 4; ++r) {
            const int o = ob + wm * 64 + mt * 16 + quad * 4 + r;
            const float bi = bo[o];
#pragma unroll
            for (int nt = 0; nt < 2; ++nt) {
                const int l = lb + wn * 32 + nt * 16 + lc;
                Y[((size_t)b * C_ + o) * L_ + l] = acc[mt][nt][r] + bi;
            }
        }
    }
}

// ---------------------------------------------------------------------------
extern "C" void kernel_launch(void* const* d_in, const int* in_sizes, int n_in,
                              void* d_out, int out_size, void* d_ws, size_t ws_size,
                              hipStream_t stream)
{
    const float* x   = (const float*)d_in[0];
    const float* Wq  = (const float*)d_in[1];
    const float* bq  = (const float*)d_in[2];
    const float* Wk  = (const float*)d_in[3];
    const float* bk  = (const float*)d_in[4];
    const float* Wv  = (const float*)d_in[5];
    const float* bv  = (const float*)d_in[6];
    const float* Wo  = (const float*)d_in[7];
    const float* bo  = (const float*)d_in[8];
    const float* erk = (const float*)d_in[9];
    const float* erv = (const float*)d_in[10];

    char* ws = (char*)d_ws;
    const size_t MB = 1024u * 1024u;
    unsigned short* xT      = (unsigned short*)(ws);             // 8 MB
    unsigned short* Qb      = (unsigned short*)(ws + 8 * MB);    // 8 MB (B,H,L,Dh)
    unsigned short* Kb      = (unsigned short*)(ws + 16 * MB);   // 8 MB (B,H,L,Dh)
    unsigned short* Vc      = (unsigned short*)(ws + 24 * MB);   // 8 MB (B,C,L)
    unsigned short* AOh     = (unsigned short*)(ws + 32 * MB);   // 8 MB f16 (B,L,C)
    unsigned short* Wqkv_hi = (unsigned short*)(ws + 40 * MB);   // 1.5 MB
    unsigned short* Wo_h    = (unsigned short*)(ws + 42 * MB);   // 0.5 MB f16
    float*          bqkv    = (float*)(ws + 43 * MB);            // 6 KB

    prep_kernel<<<256, 256, 0, stream>>>(Wq, Wk, Wv, Wo, bq, bk, bv,
                                         Wqkv_hi, Wo_h, bqkv);
    transpose_kernel<<<dim3(L_ / 32, C_ / 32, B_), 256, 0, stream>>>(x, xT);
    qkv_gemm_kernel<<<dim3(L_ / 128, 12, B_), 256, 0, stream>>>(
        Wqkv_hi, bqkv, xT, Qb, Kb, Vc);
    attn_kernel8<<<dim3(64, 8), 512, 0, stream>>>(
        Qb, Kb, Vc, erk, erv, AOh);
    out_gemm_kernel<<<dim3(L_ / 64, C_ / 128, B_), 256, 0, stream>>>(
        Wo_h, bo, AOh, (float*)d_out);
}

// Round 11
// 173.397 us; speedup vs baseline: 1.3472x; 1.0829x over previous
//
#include <hip/hip_runtime.h>
#include <math.h>

#define B_  8
#define H_  8
#define C_  512
#define L_  1024
#define DH  64
#define WIN 4

typedef __attribute__((ext_vector_type(8))) short short8;
typedef __attribute__((ext_vector_type(4))) float floatx4;

__device__ __forceinline__ unsigned short f2bf(float f) {
    unsigned int u = __float_as_uint(f);
    u = u + 0x7FFFu + ((u >> 16) & 1u);     // RNE
    return (unsigned short)(u >> 16);
}
__device__ __forceinline__ float bf2f(unsigned short h) {
    return __uint_as_float(((unsigned int)h) << 16);
}
__device__ __forceinline__ unsigned short f2h(float f) {
    _Float16 h = (_Float16)f;
    return *reinterpret_cast<unsigned short*>(&h);
}

// ---------------------------------------------------------------------------
// prep: Wq/Wk/Wv -> bf16 (packed 3x512x512), Wo -> f16, pack biases.
// ---------------------------------------------------------------------------
__global__ __launch_bounds__(256) void prep_kernel(
    const float* __restrict__ Wq, const float* __restrict__ Wk,
    const float* __restrict__ Wv, const float* __restrict__ Wo,
    const float* __restrict__ bq, const float* __restrict__ bk,
    const float* __restrict__ bv,
    unsigned short* __restrict__ Wqkv_hi,
    unsigned short* __restrict__ Wo_h,
    float* __restrict__ bqkv)
{
    const int i = blockIdx.x * 256 + threadIdx.x;   // 65536 float4 slots
    float4 v; ushort4 h;

    v = ((const float4*)Wq)[i];
    h.x = f2bf(v.x); h.y = f2bf(v.y); h.z = f2bf(v.z); h.w = f2bf(v.w);
    ((ushort4*)Wqkv_hi)[i] = h;

    v = ((const float4*)Wk)[i];
    h.x = f2bf(v.x); h.y = f2bf(v.y); h.z = f2bf(v.z); h.w = f2bf(v.w);
    ((ushort4*)Wqkv_hi)[65536 + i] = h;

    v = ((const float4*)Wv)[i];
    h.x = f2bf(v.x); h.y = f2bf(v.y); h.z = f2bf(v.z); h.w = f2bf(v.w);
    ((ushort4*)Wqkv_hi)[131072 + i] = h;

    v = ((const float4*)Wo)[i];
    h.x = f2h(v.x); h.y = f2h(v.y); h.z = f2h(v.z); h.w = f2h(v.w);
    ((ushort4*)Wo_h)[i] = h;

    if (i < 512)       bqkv[i] = bq[i];
    else if (i < 1024) bqkv[i] = bk[i - 512];
    else if (i < 1536) bqkv[i] = bv[i - 1024];
}

// ---------------------------------------------------------------------------
// x (B,C,L) fp32 -> xT bf16 (B,L,C).  32x32 LDS transpose.
// ---------------------------------------------------------------------------
__global__ __launch_bounds__(256) void transpose_kernel(
    const float* __restrict__ x, unsigned short* __restrict__ xT)
{
    __shared__ float tile[32][33];
    const int b  = blockIdx.z;
    const int cb = blockIdx.y * 32;
    const int lb = blockIdx.x * 32;
    const int t  = threadIdx.x;
    {
        const int l = t & 31, c0 = t >> 5;
#pragma unroll
        for (int p = 0; p < 4; ++p) {
            const int c = c0 + 8 * p;
            tile[c][l] = x[((size_t)b * C_ + cb + c) * L_ + lb + l];
        }
    }
    __syncthreads();
    {
        const int c = t & 31, l0 = t >> 5;
#pragma unroll
        for (int p = 0; p < 4; ++p) {
            const int l = l0 + 8 * p;
            xT[((size_t)b * L_ + lb + l) * C_ + cb + c] = f2bf(tile[c][l]);
        }
    }
}

// ---------------------------------------------------------------------------
// Fused QKV GEMM v2: double-buffered LDS + register prefetch, ONE barrier
// per K-step (the attn-proven pattern; was 2 barriers = vmcnt drain/step).
// Epilogue: single-pass dual-head LDS transpose for Q/K (sT aliases the
// K-loop buffers), direct coalesced (B,C,L) for V.
// ---------------------------------------------------------------------------
__global__ __launch_bounds__(256) void qkv_gemm_kernel(
    const unsigned short* __restrict__ Wh, const float* __restrict__ bqkv,
    const unsigned short* __restrict__ xT,
    unsigned short* __restrict__ Qb, unsigned short* __restrict__ Kb,
    unsigned short* __restrict__ Vc)
{
    // [A=0/B=1][buf][row][40] = 40 KB; epilogue sT[128][144] (36.9 KB) aliases it
    __shared__ __align__(16) unsigned short AB[2][2][128][40];

    const int b   = blockIdx.z;
    const int oB  = blockIdx.y * 128;
    const int mat = oB >> 9;                // 0=Q,1=K,2=V
    const int ob  = oB & 511;
    const int lb  = blockIdx.x * 128;
    const int t  = threadIdx.x;
    const int w = t >> 6, lane = t & 63, quad = lane >> 4, lc = lane & 15;
    const int wm = w >> 1, wn = w & 1;

    const unsigned short* Wm = Wh + (size_t)mat * C_ * C_;

    floatx4 acc[4][4];
#pragma unroll
    for (int i = 0; i < 4; ++i)
#pragma unroll
        for (int j = 0; j < 4; ++j) acc[i][j] = (floatx4)0.f;

    const int c8 = (t & 3) * 8, r0 = t >> 2;

    // stage K-step 0 into buffer 0
#pragma unroll
    for (int p = 0; p < 2; ++p) {
        *reinterpret_cast<uint4*>(&AB[0][0][r0 + 64 * p][c8]) =
            *reinterpret_cast<const uint4*>(&Wm[(size_t)(ob + r0 + 64 * p) * C_ + c8]);
        *reinterpret_cast<uint4*>(&AB[1][0][r0 + 64 * p][c8]) =
            *reinterpret_cast<const uint4*>(&xT[((size_t)b * L_ + lb + r0 + 64 * p) * C_ + c8]);
    }
    __syncthreads();

    for (int s = 0; s < 16; ++s) {
        const int cur = s & 1;

        // register prefetch of step s+1 (hidden under the MFMAs below)
        uint4 pa[2], pb[2];
        if (s < 15) {
            const int c0n = (s + 1) * 32;
#pragma unroll
            for (int p = 0; p < 2; ++p) {
                pa[p] = *reinterpret_cast<const uint4*>(
                    &Wm[(size_t)(ob + r0 + 64 * p) * C_ + c0n + c8]);
                pb[p] = *reinterpret_cast<const uint4*>(
                    &xT[((size_t)b * L_ + lb + r0 + 64 * p) * C_ + c0n + c8]);
            }
        }

        short8 a[4], bb[4];
#pragma unroll
        for (int mt = 0; mt < 4; ++mt)
            a[mt] = *reinterpret_cast<const short8*>(
                &AB[0][cur][wm * 64 + mt * 16 + lc][quad * 8]);
#pragma unroll
        for (int nt = 0; nt < 4; ++nt)
            bb[nt] = *reinterpret_cast<const short8*>(
                &AB[1][cur][wn * 64 + nt * 16 + lc][quad * 8]);
#pragma unroll
        for (int mt = 0; mt < 4; ++mt)
#pragma unroll
            for (int nt = 0; nt < 4; ++nt)
                acc[mt][nt] = __builtin_amdgcn_mfma_f32_16x16x32_bf16(
                    a[mt], bb[nt], acc[mt][nt], 0, 0, 0);

        if (s < 15) {
#pragma unroll
            for (int p = 0; p < 2; ++p) {
                *reinterpret_cast<uint4*>(&AB[0][1 - cur][r0 + 64 * p][c8]) = pa[p];
                *reinterpret_cast<uint4*>(&AB[1][1 - cur][r0 + 64 * p][c8]) = pb[p];
            }
        }
        __syncthreads();
    }

    if (mat == 2) {
        // V: direct coalesced (B,C,L)
#pragma unroll
        for (int mt = 0; mt < 4; ++mt) {
#pragma unroll
            for (int r = 0; r < 4; ++r) {
                const int o  = ob + wm * 64 + mt * 16 + quad * 4 + r;
                const float bi = bqkv[1024 + o];
#pragma unroll
                for (int nt = 0; nt < 4; ++nt) {
                    const int l = lb + wn * 64 + nt * 16 + lc;
                    Vc[((size_t)b * C_ + o) * L_ + l] = f2bf(acc[mt][nt][r] + bi);
                }
            }
        }
    } else {
        // Q/K: single-pass dual-head LDS transpose (sT aliases AB; the final
        // K-loop barrier has retired all reads of AB)
        const float scale = (mat == 0) ? 0.125f : 1.0f;
        unsigned short* dst = (mat == 0) ? Qb : Kb;
        unsigned short (*sT)[144] =
            reinterpret_cast<unsigned short (*)[144]>(&AB[0][0][0][0]);

        // wave (wm, wn): head wm, l-range wn*64..+63 — all waves concurrent
#pragma unroll
        for (int mt = 0; mt < 4; ++mt) {
#pragma unroll
            for (int r = 0; r < 4; ++r) {
                const int o  = ob + wm * 64 + mt * 16 + quad * 4 + r;
                const float bi = bqkv[mat * 512 + o];
                const int d  = mt * 16 + quad * 4 + r;
#pragma unroll
                for (int nt = 0; nt < 4; ++nt) {
                    const int l = wn * 64 + nt * 16 + lc;
                    sT[l][wm * 72 + d] = f2bf((acc[mt][nt][r] + bi) * scale);
                }
            }
        }
        __syncthreads();
        {
            const int l = t >> 1, hf = t & 1;
#pragma unroll
            for (int h01 = 0; h01 < 2; ++h01) {
                const int hgl = (ob >> 6) + h01;
                const size_t o = (((size_t)b * H_ + hgl) * L_ + lb + l) * DH + hf * 32;
                const int cbase = h01 * 72 + hf * 32;
                uint4 v0 = *reinterpret_cast<const uint4*>(&sT[l][cbase]);
                uint4 v1 = *reinterpret_cast<const uint4*>(&sT[l][cbase + 8]);
                uint4 v2 = *reinterpret_cast<const uint4*>(&sT[l][cbase + 16]);
                uint4 v3 = *reinterpret_cast<const uint4*>(&sT[l][cbase + 24]);
                *reinterpret_cast<uint4*>(&dst[o])      = v0;
                *reinterpret_cast<uint4*>(&dst[o + 8])  = v1;
                *reinterpret_cast<uint4*>(&dst[o + 16]) = v2;
                *reinterpret_cast<uint4*>(&dst[o + 24]) = v3;
            }
        }
    }
}

// ---------------------------------------------------------------------------
// Attention v8 (unchanged from R10 — measured best: 50.4 us, 16 waves/CU).
// ---------------------------------------------------------------------------
__global__ __launch_bounds__(512, 4) void attn_kernel8(
    const unsigned short* __restrict__ Qb,   // bf16 (B,H,L,Dh), pre-scaled
    const unsigned short* __restrict__ Kb,   // bf16 (B,H,L,Dh)
    const unsigned short* __restrict__ Vc,   // bf16 (B,C,L)
    const float* __restrict__ erel_k, const float* __restrict__ erel_v,
    unsigned short* __restrict__ AOh)        // f16 (B,L,C)
{
    __shared__ __align__(16) unsigned short kst[2][64][68];  // [buf][j][d]
    __shared__ __align__(16) unsigned short vst[2][64][68];  // [buf][d][j]
    __shared__ __align__(16) unsigned short Pl[8][16][68];   // per-wave P
    __shared__ float rs[128][9];
    __shared__ float rv[128][9];

    const int t  = threadIdx.x;
    const int bh = blockIdx.x;          // 0..63  (id%8==h -> XCD L2 locality)
    const int rt = blockIdx.y;          // 0..7
    const int b = bh >> 3, h = bh & 7;
    const int w = t >> 6, lane = t & 63, quad = lane >> 4, lc = lane & 15;
    const int row0 = rt * 128;
    const int rowW = row0 + w * 16;     // wave's 16 rows

    const size_t qkBase = (size_t)bh * L_ * DH;
    const size_t vBase  = ((size_t)b * C_ + h * DH) * L_;

    for (int i = lane; i < 16 * 9; i += 64) rv[w * 16 + i / 9][i % 9] = 0.f;

    // Q A-fragments (16 rows), reused across all 16 key tiles
    short8 af[2];
#pragma unroll
    for (int kk = 0; kk < 2; ++kk)
        af[kk] = *reinterpret_cast<const short8*>(
            &Qb[qkBase + (size_t)(rowW + lc) * DH + kk * 32 + quad * 8]);

    // rel-k scores via MFMA: B[n=dr][k=d] = erk[dr][d]
    {
        floatx4 rsa = (floatx4)0.f;
        const int drow = (lc < 9) ? lc : 8;
#pragma unroll
        for (int kk = 0; kk < 2; ++kk) {
            short8 bfr;
#pragma unroll
            for (int i = 0; i < 8; ++i)
                bfr[i] = (short)f2bf(erel_k[drow * 64 + kk * 32 + quad * 8 + i]);
            rsa = __builtin_amdgcn_mfma_f32_16x16x32_bf16(af[kk], bfr, rsa, 0, 0, 0);
        }
        if (lc < 9) {
#pragma unroll
            for (int r = 0; r < 4; ++r)
                rs[w * 16 + quad * 4 + r][lc] = rsa[r];
        }
    }

    // stage tile 0 (512 thr: one uint4 per thread per array covers 64x64)
    const int jr = t >> 3, jc = (t & 7) * 8;
    *reinterpret_cast<uint4*>(&kst[0][jr][jc]) =
        *reinterpret_cast<const uint4*>(&Kb[qkBase + (size_t)jr * DH + jc]);
    *reinterpret_cast<uint4*>(&vst[0][jr][jc]) =
        *reinterpret_cast<const uint4*>(&Vc[vBase + (size_t)jr * L_ + jc]);
    __syncthreads();

    short8 ones;
#pragma unroll
    for (int j = 0; j < 8; ++j) ones[j] = (short)0x3F80;

    floatx4 acc_o[4], acc_l = (floatx4)0.f;
#pragma unroll
    for (int nt = 0; nt < 4; ++nt) acc_o[nt] = (floatx4)0.f;

    for (int jt = 0; jt < L_ / 64; ++jt) {
        const int j0  = jt * 64;
        const int cur = jt & 1;

        // register prefetch of next tile
        uint4 pk, pv;
        if (jt < L_ / 64 - 1) {
            const int j0n = j0 + 64;
            pk = *reinterpret_cast<const uint4*>(
                &Kb[qkBase + (size_t)(j0n + jr) * DH + jc]);
            pv = *reinterpret_cast<const uint4*>(
                &Vc[vBase + (size_t)jr * L_ + j0n + jc]);
        }

        // S = Q K^T
        floatx4 sacc[4];
#pragma unroll
        for (int nt = 0; nt < 4; ++nt) sacc[nt] = (floatx4)0.f;
#pragma unroll
        for (int nt = 0; nt < 4; ++nt)
#pragma unroll
            for (int kk = 0; kk < 2; ++kk) {
                const short8 kf = *reinterpret_cast<const short8*>(
                    &kst[cur][nt * 16 + lc][kk * 32 + quad * 8]);
                sacc[nt] = __builtin_amdgcn_mfma_f32_16x16x32_bf16(af[kk], kf, sacc[nt], 0, 0, 0);
            }

        // windowed rel-k bias (near-diagonal tiles only)
        const bool nearD = (j0 <= rowW + 15 + WIN) && (j0 + 63 >= rowW - WIN);
        if (nearD) {
#pragma unroll
            for (int nt = 0; nt < 4; ++nt) {
                const int jg = j0 + nt * 16 + lc;
#pragma unroll
                for (int r = 0; r < 4; ++r) {
                    const int diff = jg - (rowW + quad * 4 + r);
                    if (diff >= -WIN && diff <= WIN)
                        sacc[nt][r] += rs[w * 16 + quad * 4 + r][diff + WIN];
                }
            }
        }

        // exp (no max subtraction; scores bounded ~|6|), P -> LDS bf16
#pragma unroll
        for (int nt = 0; nt < 4; ++nt)
#pragma unroll
            for (int r = 0; r < 4; ++r)
                Pl[w][quad * 4 + r][nt * 16 + lc] = f2bf(__expf(sacc[nt][r]));

        // rel-v prob accumulation (gated; wave-private rows, in-order DS)
        if (nearD) {
            for (int idx = lane; idx < 16 * 9; idx += 64) {
                const int r16 = idx / 9, dr = idx % 9;
                const int jg = rowW + r16 + dr - WIN;
                if (jg >= j0 && jg < j0 + 64 && jg >= 0 && jg < L_)
                    rv[w * 16 + r16][dr] += bf2f(Pl[w][r16][jg - j0]);
            }
        }

        // P back as A-fragments
        short8 pf[2];
#pragma unroll
        for (int kk = 0; kk < 2; ++kk)
            pf[kk] = *reinterpret_cast<const short8*>(&Pl[w][lc][kk * 32 + quad * 8]);

        // row sums via MFMA
#pragma unroll
        for (int kk = 0; kk < 2; ++kk)
            acc_l = __builtin_amdgcn_mfma_f32_16x16x32_bf16(pf[kk], ones, acc_l, 0, 0, 0);

        // O += P V  (V B-frags from LDS)
#pragma unroll
        for (int nt = 0; nt < 4; ++nt)
#pragma unroll
            for (int kk = 0; kk < 2; ++kk) {
                const short8 vf = *reinterpret_cast<const short8*>(
                    &vst[cur][nt * 16 + lc][kk * 32 + quad * 8]);
                acc_o[nt] = __builtin_amdgcn_mfma_f32_16x16x32_bf16(pf[kk], vf, acc_o[nt], 0, 0, 0);
            }

        // commit prefetched tile, then sync
        if (jt < L_ / 64 - 1) {
            *reinterpret_cast<uint4*>(&kst[1 - cur][jr][jc]) = pk;
            *reinterpret_cast<uint4*>(&vst[1 - cur][jr][jc]) = pv;
        }
        __syncthreads();
    }

    // epilogue: rel-v term, normalize, transpose via Pl, full-line f16 stores
#pragma unroll
    for (int nt = 0; nt < 4; ++nt) {
        const int d = nt * 16 + lc;
        float ev[9];
#pragma unroll
        for (int dr = 0; dr < 9; ++dr) ev[dr] = erel_v[dr * 64 + d];
#pragma unroll
        for (int r = 0; r < 4; ++r) {
            const int rloc = w * 16 + quad * 4 + r;
            float v = acc_o[nt][r];
#pragma unroll
            for (int dr = 0; dr < 9; ++dr) v += rv[rloc][dr] * ev[dr];
            Pl[w][quad * 4 + r][nt * 16 + lc] = f2h(v / acc_l[r]);
        }
    }
    {
        const int row = lane >> 2, ds8 = (lane & 3) * 16;
        const uint4 q0 = *reinterpret_cast<const uint4*>(&Pl[w][row][ds8]);
        const uint4 q1 = *reinterpret_cast<const uint4*>(&Pl[w][row][ds8 + 8]);
        const size_t o = ((size_t)b * L_ + rowW + row) * C_ + h * 64 + ds8;
        *reinterpret_cast<uint4*>(&AOh[o])     = q0;
        *reinterpret_cast<uint4*>(&AOh[o + 8]) = q1;
    }
}

// ---------------------------------------------------------------------------
// Output projection v2: 1-term f16, double-buffered LDS + register prefetch,
// one barrier per K-step.  M-tile 128 x N-tile 64 x K=512.
// ---------------------------------------------------------------------------
__global__ __launch_bounds__(256) void out_gemm_kernel(
    const unsigned short* __restrict__ Wh,
    const float* __restrict__ bo,
    const unsigned short* __restrict__ Ah,
    float* __restrict__ Y)
{
    __shared__ __align__(16) unsigned short Asb[2][128][40];
    __shared__ __align__(16) unsigned short Bsb[2][64][40];

    const int b  = blockIdx.z;
    const int ob = blockIdx.y * 128;
    const int lb = blockIdx.x * 64;
    const int t  = threadIdx.x;
    const int w = t >> 6, lane = t & 63, quad = lane >> 4, lc = lane & 15;
    const int wm = w >> 1, wn = w & 1;

    floatx4 acc[4][2];
#pragma unroll
    for (int i = 0; i < 4; ++i)
#pragma unroll
        for (int j = 0; j < 2; ++j) acc[i][j] = (floatx4)0.f;

    const int c8 = (t & 3) * 8, r0 = t >> 2;

    // stage step 0
#pragma unroll
    for (int p = 0; p < 2; ++p)
        *reinterpret_cast<uint4*>(&Asb[0][r0 + 64 * p][c8]) =
            *reinterpret_cast<const uint4*>(&Wh[(size_t)(ob + r0 + 64 * p) * C_ + c8]);
    *reinterpret_cast<uint4*>(&Bsb[0][r0][c8]) =
        *reinterpret_cast<const uint4*>(&Ah[((size_t)b * L_ + lb + r0) * C_ + c8]);
    __syncthreads();

    for (int s = 0; s < 16; ++s) {
        const int cur = s & 1;

        uint4 pa[2], pb;
        if (s < 15) {
            const int c0n = (s + 1) * 32;
#pragma unroll
            for (int p = 0; p < 2; ++p)
                pa[p] = *reinterpret_cast<const uint4*>(
                    &Wh[(size_t)(ob + r0 + 64 * p) * C_ + c0n + c8]);
            pb = *reinterpret_cast<const uint4*>(
                &Ah[((size_t)b * L_ + lb + r0) * C_ + c0n + c8]);
        }

        short8 ah[4], bhf[2];
#pragma unroll
        for (int mt = 0; mt < 4; ++mt)
            ah[mt] = *reinterpret_cast<const short8*>(
                &Asb[cur][wm * 64 + mt * 16 + lc][quad * 8]);
#pragma unroll
        for (int nt = 0; nt < 2; ++nt)
            bhf[nt] = *reinterpret_cast<const short8*>(
                &Bsb[cur][wn * 32 + nt * 16 + lc][quad * 8]);
#pragma unroll
        for (int mt = 0; mt < 4; ++mt)
#pragma unroll
            for (int nt = 0; nt < 2; ++nt)
                acc[mt][nt] = __builtin_amdgcn_mfma_f32_16x16x32_f16(
                    ah[mt], bhf[nt], acc[mt][nt], 0, 0, 0);

        if (s < 15) {
#pragma unroll
            for (int p = 0; p < 2; ++p)
                *reinterpret_cast<uint4*>(&Asb[1 - cur][r0 + 64 * p][c8]) = pa[p];
            *reinterpret_cast<uint4*>(&Bsb[1 - cur][r0][c8]) = pb;
        }
        __syncthreads();
    }

#pragma unroll
    for (int mt = 0; mt < 4; ++mt) {
#pragma unroll
        for (int r = 0; r < 4; ++r) {
            const int o = ob + wm * 64 + mt * 16 + quad * 4 + r;
            const float bi = bo[o];
#pragma unroll
            for (int nt = 0; nt < 2; ++nt) {
                const int l = lb + wn * 32 + nt * 16 + lc;
                Y[((size_t)b * C_ + o) * L_ + l] = acc[mt][nt][r] + bi;
            }
        }
    }
}

// ---------------------------------------------------------------------------
extern "C" void kernel_launch(void* const* d_in, const int* in_sizes, int n_in,
                              void* d_out, int out_size, void* d_ws, size_t ws_size,
                              hipStream_t stream)
{
    const float* x   = (const float*)d_in[0];
    const float* Wq  = (const float*)d_in[1];
    const float* bq  = (const float*)d_in[2];
    const float* Wk  = (const float*)d_in[3];
    const float* bk  = (const float*)d_in[4];
    const float* Wv  = (const float*)d_in[5];
    const float* bv  = (const float*)d_in[6];
    const float* Wo  = (const float*)d_in[7];
    const float* bo  = (const float*)d_in[8];
    const float* erk = (const float*)d_in[9];
    const float* erv = (const float*)d_in[10];

    char* ws = (char*)d_ws;
    const size_t MB = 1024u * 1024u;
    unsigned short* xT      = (unsigned short*)(ws);             // 8 MB
    unsigned short* Qb      = (unsigned short*)(ws + 8 * MB);    // 8 MB (B,H,L,Dh)
    unsigned short* Kb      = (unsigned short*)(ws + 16 * MB);   // 8 MB (B,H,L,Dh)
    unsigned short* Vc      = (unsigned short*)(ws + 24 * MB);   // 8 MB (B,C,L)
    unsigned short* AOh     = (unsigned short*)(ws + 32 * MB);   // 8 MB f16 (B,L,C)
    unsigned short* Wqkv_hi = (unsigned short*)(ws + 40 * MB);   // 1.5 MB
    unsigned short* Wo_h    = (unsigned short*)(ws + 42 * MB);   // 0.5 MB f16
    float*          bqkv    = (float*)(ws + 43 * MB);            // 6 KB

    prep_kernel<<<256, 256, 0, stream>>>(Wq, Wk, Wv, Wo, bq, bk, bv,
                                         Wqkv_hi, Wo_h, bqkv);
    transpose_kernel<<<dim3(L_ / 32, C_ / 32, B_), 256, 0, stream>>>(x, xT);
    qkv_gemm_kernel<<<dim3(L_ / 128, 12, B_), 256, 0, stream>>>(
        Wqkv_hi, bqkv, xT, Qb, Kb, Vc);
    attn_kernel8<<<dim3(64, 8), 512, 0, stream>>>(
        Qb, Kb, Vc, erk, erv, AOh);
    out_gemm_kernel<<<dim3(L_ / 64, C_ / 128, B_), 256, 0, stream>>>(
        Wo_h, bo, AOh, (float*)d_out);
}